// Round 3
// baseline (569.653 us; speedup 1.0000x reference)
//
#include <hip/hip_runtime.h>

#define S_DIM 4096
#define E_DIM 1024
#define H_DIM 8

typedef __bf16 bf16x8 __attribute__((ext_vector_type(8)));
typedef float  f32x4  __attribute__((ext_vector_type(4)));

// Async global->LDS, 16B per lane. LDS dest is wave-uniform base + lane*16.
__device__ __forceinline__ void async16(const __bf16* gsrc, __bf16* lbase, int lane)
{
#if __has_builtin(__builtin_amdgcn_global_load_lds)
    __builtin_amdgcn_global_load_lds(
        (const __attribute__((address_space(1))) unsigned int*)gsrc,
        (__attribute__((address_space(3))) unsigned int*)lbase, 16, 0, 0);
#else
    ((int4*)lbase)[lane] = *(const int4*)gsrc;
#endif
}

// ---------------------------------------------------------------------------
// Operand staging into LDS (bf16 sources only).
// MODE 0: NT [mn,k] k-contig -> async global_load_lds, tile stride 64 (no pad)
// MODE 2: TN [k,mn] k-major  -> transpose via packed b64, static XOR swizzle,
//         tile stride 72. True col c lives at LDS row (c&~7)|((c&7)^((c>>3)&7)).
// ---------------------------------------------------------------------------
template <int MODE>
__device__ __forceinline__ void stage_op(const __bf16* __restrict__ src, int ld,
                                         int mn0, int k0, __bf16* lds, int tid)
{
    if constexpr (MODE == 0) {
        const int w = tid >> 6, l = tid & 63;
        const int r8 = l >> 3, c8 = (l & 7) << 3;
#pragma unroll
        for (int i = 0; i < 4; i++) {
            const int rbase = w * 32 + i * 8;
            const __bf16* g = src + (size_t)(mn0 + rbase + r8) * ld + k0 + c8;
            async16(g, &lds[rbase * 64], l);
        }
    } else {
        // cols mn0 + (tid&15)*8 .. +8 ; krows k0 + (tid>>4)*4 .. +4
        const int cg = tid & 15, kg = tid >> 4;
        __bf16 h[4][8];
#pragma unroll
        for (int r = 0; r < 4; r++) {
            const __bf16* s = src + (size_t)(k0 + kg * 4 + r) * ld + mn0 + cg * 8;
            *(int4*)&h[r][0] = *(const int4*)s;
        }
        const int xr = cg & 7;
#pragma unroll
        for (int j = 0; j < 8; j++) {            // j static -> h[][] in VGPRs
            union { __bf16 q[4]; unsigned long long v; } u;
            u.q[0]=h[0][j]; u.q[1]=h[1][j]; u.q[2]=h[2][j]; u.q[3]=h[3][j];
            const int scol = cg * 8 + (j ^ xr);  // swizzle in address only
            *(unsigned long long*)&lds[scol * 72 + kg * 4] = u.v;
        }
    }
}

// ---------------------------------------------------------------------------
// 128x128-tile bf16 MFMA GEMM (kept for TN-staged operands: G, Mcat).
// OUT: 0=bf16 store, 1=fp32 store, 2=fp32 atomicAdd (split-K; bias ignored).
// ---------------------------------------------------------------------------
template <int AM, int BM, int OUT>
__global__ __launch_bounds__(256) void gemm128(
    const __bf16* __restrict__ Ag, const __bf16* __restrict__ Bg,
    void* __restrict__ Cg, const float* __restrict__ biasg,
    int Klen, int kPerZ, int lda, int ldb, int ldc,
    long long sA, long long sB, long long sC, float scale)
{
    __shared__ __bf16 As[128 * 72];
    __shared__ __bf16 Bs[128 * 72];
    constexpr int SA = (AM == 2) ? 72 : 64;
    constexpr int SB = (BM == 2) ? 72 : 64;

    const int tid  = threadIdx.x;
    const int lane = tid & 63;
    const int wave = tid >> 6;
    const int t    = lane & 15;
    const int quad = lane >> 4;
    const int wm   = wave >> 1;
    const int wn   = wave & 1;
    const int m0   = blockIdx.y * 128;
    const int n0   = blockIdx.x * 128;
    const size_t zi = blockIdx.z;

    const __bf16* A = (kPerZ == 0) ? Ag + zi * sA : Ag;
    const __bf16* B = (kPerZ == 0) ? Bg + zi * sB : Bg;
    const int kbeg = kPerZ ? (int)zi * kPerZ : 0;

    int rowA[4], rowB[4];
#pragma unroll
    for (int i = 0; i < 4; i++) {
        int ra = wm * 64 + i * 16 + t;
        int rb = wn * 64 + i * 16 + t;
        rowA[i] = (AM == 2) ? (ra ^ ((ra >> 3) & 7)) : ra;
        rowB[i] = (BM == 2) ? (rb ^ ((rb >> 3) & 7)) : rb;
    }

    f32x4 acc[4][4];
#pragma unroll
    for (int i = 0; i < 4; i++)
#pragma unroll
        for (int j = 0; j < 4; j++) { f32x4 z = {0.f,0.f,0.f,0.f}; acc[i][j] = z; }

    for (int k0 = kbeg; k0 < kbeg + Klen; k0 += 64) {
        stage_op<AM>(A, lda, m0, k0, As, tid);
        stage_op<BM>(B, ldb, n0, k0, Bs, tid);
        __syncthreads();
#pragma unroll
        for (int kk = 0; kk < 2; kk++) {
            bf16x8 af[4], bfv[4];
#pragma unroll
            for (int i = 0; i < 4; i++)
                af[i] = *(const bf16x8*)(&As[rowA[i] * SA + kk*32 + quad*8]);
#pragma unroll
            for (int j = 0; j < 4; j++)
                bfv[j] = *(const bf16x8*)(&Bs[rowB[j] * SB + kk*32 + quad*8]);
#pragma unroll
            for (int i = 0; i < 4; i++)
#pragma unroll
                for (int j = 0; j < 4; j++)
                    acc[i][j] = __builtin_amdgcn_mfma_f32_16x16x32_bf16(af[i], bfv[j], acc[i][j], 0, 0, 0);
        }
        __syncthreads();
    }

#pragma unroll
    for (int i = 0; i < 4; i++) {
        const int rowb = m0 + wm*64 + i*16 + quad*4;
#pragma unroll
        for (int j = 0; j < 4; j++) {
            const int col = n0 + wn*64 + j*16 + t;
            const float bv = biasg ? biasg[col] : 0.f;
#pragma unroll
            for (int r = 0; r < 4; r++) {
                const float v = acc[i][j][r] * scale + bv;
                if constexpr (OUT == 0) {
                    __bf16* C = (__bf16*)Cg + zi * sC;
                    C[(size_t)(rowb + r) * ldc + col] = (__bf16)v;
                } else if constexpr (OUT == 1) {
                    float* C = (float*)Cg + zi * sC;
                    C[(size_t)(rowb + r) * ldc + col] = v;
                } else {
                    float* C = (float*)Cg;
                    atomicAdd(&C[(size_t)(rowb + r) * ldc + col], v);
                }
            }
        }
    }
}

// ---------------------------------------------------------------------------
// 128x128 NT-NT GEMM, m97 structure, 32 KiB LDS (5 blocks/CU capacity),
// 1D grid with XCD-colocating decode: bid%8 selects the XCD chunk; each
// chunk = (nMt/8) M-tiles x 8 N-tiles, so blocks sharing an A-panel (same
// m-tile) or B-panel land on the SAME XCD's L2 (assumes round-robin
// block->XCD by linear id; if wrong, perf-neutral).
// nNt is hardcoded 8 (all call sites have N = 1024 = 8 tiles).
// B head-select for block-diagonal batched B: B += (m0>>10)*sBhead.
// Split-K via kPerZ: zi = bid / (nMt*8); kbeg = zi*kPerZ.
// OUT: 0=bf16 store, 1=fp32 store at Cg+zi*sC, 2=fp32 atomicAdd.
// ---------------------------------------------------------------------------
template <int OUT>
__global__ __launch_bounds__(256) void gemm128x(
    const __bf16* __restrict__ Ag, const __bf16* __restrict__ Bg,
    void* __restrict__ Cg, int Klen, int kPerZ,
    int lda, int ldb, int ldc, long long sBhead, long long sC, int nMt)
{
    __shared__ __bf16 As[128 * 64];
    __shared__ __bf16 Bs[128 * 64];

    const int tid  = threadIdx.x;
    const int lane = tid & 63;
    const int wave = tid >> 6;
    const int t    = lane & 15;
    const int quad = lane >> 4;
    const int wm   = wave >> 1;
    const int wn   = wave & 1;

    const int bid = blockIdx.x;
    const int bpz = nMt << 3;              // blocks per K-slice (nNt = 8)
    const int zi  = bid / bpz;
    const int rr  = bid - zi * bpz;
    const int xcd = rr & 7;
    const int s   = rr >> 3;
    const int mt  = xcd * (nMt >> 3) + (s >> 3);
    const int nt  = s & 7;
    const int m0  = mt * 128;
    const int n0  = nt * 128;
    const int kbeg = zi * kPerZ;

    const __bf16* B = Bg + (size_t)(m0 >> 10) * sBhead;

    f32x4 acc[4][4];
#pragma unroll
    for (int i = 0; i < 4; i++)
#pragma unroll
        for (int j = 0; j < 4; j++) { f32x4 z = {0.f,0.f,0.f,0.f}; acc[i][j] = z; }

    for (int k0 = kbeg; k0 < kbeg + Klen; k0 += 64) {
        stage_op<0>(Ag, lda, m0, k0, As, tid);
        stage_op<0>(B,  ldb, n0, k0, Bs, tid);
        __syncthreads();
#pragma unroll
        for (int kk = 0; kk < 2; kk++) {
            bf16x8 af[4], bfv[4];
#pragma unroll
            for (int i = 0; i < 4; i++)
                af[i] = *(const bf16x8*)(&As[(wm*64 + i*16 + t) * 64 + kk*32 + quad*8]);
#pragma unroll
            for (int j = 0; j < 4; j++)
                bfv[j] = *(const bf16x8*)(&Bs[(wn*64 + j*16 + t) * 64 + kk*32 + quad*8]);
#pragma unroll
            for (int i = 0; i < 4; i++)
#pragma unroll
                for (int j = 0; j < 4; j++)
                    acc[i][j] = __builtin_amdgcn_mfma_f32_16x16x32_bf16(af[i], bfv[j], acc[i][j], 0, 0, 0);
        }
        __syncthreads();
    }

#pragma unroll
    for (int i = 0; i < 4; i++) {
        const int rowb = m0 + wm*64 + i*16 + quad*4;
#pragma unroll
        for (int j = 0; j < 4; j++) {
            const int col = n0 + wn*64 + j*16 + t;
#pragma unroll
            for (int r = 0; r < 4; r++) {
                const float v = acc[i][j][r];
                if constexpr (OUT == 0) {
                    ((__bf16*)Cg)[(size_t)(rowb + r) * ldc + col] = (__bf16)v;
                } else if constexpr (OUT == 1) {
                    float* C = (float*)Cg + (size_t)zi * sC;
                    C[(size_t)(rowb + r) * ldc + col] = v;
                } else {
                    atomicAdd(&((float*)Cg)[(size_t)(rowb + r) * ldc + col], v);
                }
            }
        }
    }
}

// fp32 -> bf16, 8 elems/thread, exact-size grid (n multiple of 2048).
__global__ __launch_bounds__(256) void cvt_bf16(
    const float* __restrict__ in, __bf16* __restrict__ out)
{
    const size_t i = ((size_t)blockIdx.x * 256 + threadIdx.x) * 8;
    float4 a = *(const float4*)(in + i);
    float4 b = *(const float4*)(in + i + 4);
    union { __bf16 h[8]; int4 v; } u;
    u.h[0]=(__bf16)a.x; u.h[1]=(__bf16)a.y; u.h[2]=(__bf16)a.z; u.h[3]=(__bf16)a.w;
    u.h[4]=(__bf16)b.x; u.h[5]=(__bf16)b.y; u.h[6]=(__bf16)b.z; u.h[7]=(__bf16)b.w;
    *(int4*)(out + i) = u.v;
}

// u[e] = sum_s x[s][e].  64 blocks x 64 rows; u pre-zeroed.
__global__ __launch_bounds__(256) void colsum_u(const float* __restrict__ x, float* __restrict__ u)
{
    const int c = threadIdx.x * 4;
    float4 a = {0.f,0.f,0.f,0.f};
    const int r0 = blockIdx.x * 64;
    for (int r = 0; r < 64; r++) {
        float4 v = *(const float4*)(x + (size_t)(r0 + r) * E_DIM + c);
        a.x += v.x; a.y += v.y; a.z += v.z; a.w += v.w;
    }
    atomicAdd(&u[c+0], a.x); atomicAdd(&u[c+1], a.y);
    atomicAdd(&u[c+2], a.z); atomicAdd(&u[c+3], a.w);
}

// kq[r] = Wk[r,:]·u ; qq[r] = Wq[r,:]·u  (r = h*E+j, 8192 rows each)
__global__ __launch_bounds__(256) void gemv_u(
    const float* __restrict__ Wk, const float* __restrict__ Wq,
    const float* __restrict__ u, float* __restrict__ kq, float* __restrict__ qq)
{
    const int gw = blockIdx.x * 4 + (threadIdx.x >> 6);
    const int lane = threadIdx.x & 63;
    const float* W = (gw < 8192) ? Wk + (size_t)gw * E_DIM
                                 : Wq + (size_t)(gw - 8192) * E_DIM;
    float s = 0.f;
#pragma unroll
    for (int i = 0; i < 4; i++) {
        float4 w = *(const float4*)(W + lane*16 + i*4);
        float4 z = *(const float4*)(u + lane*16 + i*4);
        s += w.x*z.x + w.y*z.y + w.z*z.z + w.w*z.w;
    }
#pragma unroll
    for (int o = 32; o > 0; o >>= 1) s += __shfl_down(s, o);
    if (lane == 0) { if (gw < 8192) kq[gw] = s; else qq[gw - 8192] = s; }
}

// zb[h*E+f] = sum_o bv[h][o] * A[h][o][f]; zb pre-zeroed. grid (4,8,4)
__global__ __launch_bounds__(256) void colsum_zb(
    const __bf16* __restrict__ Ab, const float* __restrict__ bv, float* __restrict__ zb)
{
    const int h = blockIdx.y;
    const int f = blockIdx.x * 256 + threadIdx.x;
    const int o0 = blockIdx.z * 256;
    const __bf16* A = Ab + (size_t)h * E_DIM * E_DIM + (size_t)o0 * E_DIM + f;
    const float* bvh = bv + h * E_DIM + o0;
    float s = 0.f;
    for (int o = 0; o < 256; o++) s += bvh[o] * (float)A[(size_t)o * E_DIM];
    atomicAdd(&zb[h * E_DIM + f], s);
}

// oc[g] = zb·Wz[g,:] + bz[g]   (K=8192, one wave per row)
__global__ __launch_bounds__(256) void gemv_oc(
    const float* __restrict__ Wz, const float* __restrict__ zb,
    const float* __restrict__ bz, float* __restrict__ oc)
{
    const int gw = blockIdx.x * 4 + (threadIdx.x >> 6);
    const int lane = threadIdx.x & 63;
    const float* W = Wz + (size_t)gw * (H_DIM * E_DIM);
    float s = 0.f;
#pragma unroll
    for (int i = 0; i < 32; i++) {
        float4 w = *(const float4*)(W + i*256 + lane*4);
        float4 z = *(const float4*)(zb + i*256 + lane*4);
        s += w.x*z.x + w.y*z.y + w.z*z.z + w.w*z.w;
    }
#pragma unroll
    for (int o = 32; o > 0; o >>= 1) s += __shfl_down(s, o);
    if (lane == 0) oc[gw] = s + bz[gw];
}

// softmax over f with fused rank-1 bias terms and 1/sqrt(E) scale.
__global__ __launch_bounds__(256) void softmax_fused(
    const float* __restrict__ Sc, const float* __restrict__ kq,
    const float* __restrict__ qq, const float* __restrict__ bk,
    const float* __restrict__ bq, __bf16* __restrict__ Aout)
{
    __shared__ float red[4];
    const int row = blockIdx.x;
    const int h = row >> 10;
    const int tid = threadIdx.x, lane = tid & 63, wave = tid >> 6;
    const float kqj = kq[row], bkj = bk[row];
    const float cst = (float)S_DIM * bkj;

    float4 v = ((const float4*)(Sc + (size_t)row * E_DIM))[tid];
    const int c = tid * 4;
    float4 qv = *(const float4*)(qq + (h << 10) + c);
    float4 bv = *(const float4*)(bq + (h << 10) + c);
    v.x = (v.x + kqj*bv.x + bkj*qv.x + cst*bv.x) * 0.03125f;
    v.y = (v.y + kqj*bv.y + bkj*qv.y + cst*bv.y) * 0.03125f;
    v.z = (v.z + kqj*bv.z + bkj*qv.z + cst*bv.z) * 0.03125f;
    v.w = (v.w + kqj*bv.w + bkj*qv.w + cst*bv.w) * 0.03125f;

    float m = fmaxf(fmaxf(v.x, v.y), fmaxf(v.z, v.w));
#pragma unroll
    for (int o = 32; o > 0; o >>= 1) m = fmaxf(m, __shfl_down(m, o));
    if (lane == 0) red[wave] = m;
    __syncthreads();
    m = fmaxf(fmaxf(red[0], red[1]), fmaxf(red[2], red[3]));
    __syncthreads();

    const float e0 = __expf(v.x - m), e1 = __expf(v.y - m);
    const float e2 = __expf(v.z - m), e3 = __expf(v.w - m);
    float s = e0 + e1 + e2 + e3;
#pragma unroll
    for (int o = 32; o > 0; o >>= 1) s += __shfl_down(s, o);
    if (lane == 0) red[wave] = s;
    __syncthreads();
    s = red[0] + red[1] + red[2] + red[3];
    const float inv = 1.f / s;

    __bf16* out = Aout + (size_t)row * E_DIM + c;
    out[0] = (__bf16)(e0*inv); out[1] = (__bf16)(e1*inv);
    out[2] = (__bf16)(e2*inv); out[3] = (__bf16)(e3*inv);
}

// LN + residual. X = sum of NPART fp32 partials (stride S*E) + optional
// per-column bias cb. out = LN(X)*g + b + resid.
template <int NPART, bool CB, bool WRITE_BF16>
__global__ __launch_bounds__(256) void ln_residual(
    const float* __restrict__ X, const float* __restrict__ cb,
    const float* __restrict__ resid,
    const float* __restrict__ g, const float* __restrict__ b,
    __bf16* __restrict__ outB, float* __restrict__ outF)
{
    __shared__ float redS[4], redQ[4];
    const int row = blockIdx.x;
    const int tid = threadIdx.x, lane = tid & 63, wave = tid >> 6;
    const size_t SE = (size_t)S_DIM * E_DIM;

    float4 v = ((const float4*)(X + (size_t)row * E_DIM))[tid];
#pragma unroll
    for (int p = 1; p < NPART; ++p) {
        float4 v1 = ((const float4*)(X + (size_t)p * SE + (size_t)row * E_DIM))[tid];
        v.x += v1.x; v.y += v1.y; v.z += v1.z; v.w += v1.w;
    }
    if constexpr (CB) {
        float4 cv = ((const float4*)cb)[tid];
        v.x += cv.x; v.y += cv.y; v.z += cv.z; v.w += cv.w;
    }
    float s = v.x + v.y + v.z + v.w;
    float q = v.x*v.x + v.y*v.y + v.z*v.z + v.w*v.w;
#pragma unroll
    for (int o = 32; o > 0; o >>= 1) { s += __shfl_down(s, o); q += __shfl_down(q, o); }
    if (lane == 0) { redS[wave] = s; redQ[wave] = q; }
    __syncthreads();
    s = redS[0]+redS[1]+redS[2]+redS[3];
    q = redQ[0]+redQ[1]+redQ[2]+redQ[3];

    const float mean = s * (1.f / E_DIM);
    const float var  = q * (1.f / E_DIM) - mean * mean;
    const float rstd = rsqrtf(var + 1e-5f);

    const int c0 = tid * 4;
    float4 rv = ((const float4*)(resid + (size_t)row * E_DIM))[tid];
    const float res[4] = {rv.x, rv.y, rv.z, rv.w};
    const float* vp = &v.x;
#pragma unroll
    for (int i = 0; i < 4; i++) {
        const float o = (vp[i] - mean) * rstd * g[c0+i] + b[c0+i] + res[i];
        outF[(size_t)row * E_DIM + c0 + i] = o;
        if constexpr (WRITE_BF16) outB[(size_t)row * E_DIM + c0 + i] = (__bf16)o;
    }
}

// ---------------------------------------------------------------------------
extern "C" void kernel_launch(void* const* d_in, const int* in_sizes, int n_in,
                              void* d_out, int out_size, void* d_ws, size_t ws_size,
                              hipStream_t stream)
{
    const float* x   = (const float*)d_in[0];
    const float* Wq  = (const float*)d_in[1];
    const float* bq  = (const float*)d_in[2];
    const float* Wk  = (const float*)d_in[3];
    const float* bk  = (const float*)d_in[4];
    const float* Wv  = (const float*)d_in[5];
    const float* bv  = (const float*)d_in[6];
    const float* Wz  = (const float*)d_in[7];
    const float* bz  = (const float*)d_in[8];
    const float* g1  = (const float*)d_in[9];
    const float* b1  = (const float*)d_in[10];
    const float* Wf  = (const float*)d_in[11];
    const float* bfp = (const float*)d_in[12];
    const float* g2  = (const float*)d_in[13];
    const float* b2  = (const float*)d_in[14];

    char* ws = (char*)d_ws;
    const long long EE = (long long)E_DIM * E_DIM;
    const long long SE = (long long)S_DIM * E_DIM;
    const size_t MB = 1024ull * 1024ull;

    // bf16 operand copies
    __bf16* xb   = (__bf16*)(ws);             //  8 MiB
    __bf16* Wqb  = (__bf16*)(ws +   8*MB);    // 16 MiB
    __bf16* Wkb  = (__bf16*)(ws +  24*MB);    // 16 MiB
    __bf16* Wvb  = (__bf16*)(ws +  40*MB);    // 16 MiB
    __bf16* Wzb  = (__bf16*)(ws +  56*MB);    // 16 MiB
    __bf16* Wfb  = (__bf16*)(ws +  72*MB);    //  2 MiB
    float*  Gf   = (float*) (ws +  74*MB);    //  4 MiB
    __bf16* Gb   = (__bf16*)(ws +  78*MB);    //  2 MiB
    float*  PTf  = (float*) (ws +  80*MB);    //  4 MiB
    __bf16* PTb  = (__bf16*)(ws +  84*MB);    //  2 MiB
    float*  u    = (float*) (ws +  86*MB);
    float*  kq   = (float*) (ws +  86*MB +  65536);
    float*  qq   = (float*) (ws +  86*MB + 131072);
    float*  zb   = (float*) (ws +  86*MB + 196608);
    float*  oc   = (float*) (ws +  86*MB + 262144);
    __bf16* LN1b = (__bf16*)(ws +  87*MB);    //  8 MiB
    float*  LN1f = (float*) (ws +  95*MB);    // 16 MiB
    __bf16* Tb   = (__bf16*)(ws + 111*MB);    // 16 MiB  (dead after scores)
    float*  Sc   = (float*) (ws + 127*MB);    // 32 MiB  (dead after softmax)
    __bf16* Ab   = (__bf16*)(ws + 159*MB);    // 16 MiB  (dead after Mcat/zb)
    __bf16* Mcat = (__bf16*)(ws + 175*MB);    // 16 MiB  (dead after PT; end 191)
    float*  Ob   = (float*) (ws + 111*MB);    // 32 MiB  2 partials (over Tb+Sc lo)
    float*  FNb  = (float*) (ws + 111*MB);    // 32 MiB  2 partials (Ob dead after LN1)

    dim3 blk(256);

    // zero accumulators (ws is 0xAA-poisoned). Sc is atomically accumulated.
    hipMemsetAsync(Gf,  0, 4*MB, stream);
    hipMemsetAsync(PTf, 0, 4*MB, stream);
    hipMemsetAsync(Sc,  0, 32*MB, stream);
    hipMemsetAsync(u,   0, E_DIM*4, stream);
    hipMemsetAsync(zb,  0, H_DIM*E_DIM*4, stream);

    // fp32 -> bf16 operand conversions
    cvt_bf16<<<dim3(2048), blk, 0, stream>>>(x,  xb);
    cvt_bf16<<<dim3(4096), blk, 0, stream>>>(Wq, Wqb);
    cvt_bf16<<<dim3(4096), blk, 0, stream>>>(Wk, Wkb);
    cvt_bf16<<<dim3(4096), blk, 0, stream>>>(Wv, Wvb);
    cvt_bf16<<<dim3(4096), blk, 0, stream>>>(Wz, Wzb);
    cvt_bf16<<<dim3(512),  blk, 0, stream>>>(Wf, Wfb);

    // u = colsum(x); kq = Wk u; qq = Wq u  (fp32 exact)
    colsum_u<<<dim3(64), blk, 0, stream>>>(x, u);
    gemv_u<<<dim3(4096), blk, 0, stream>>>(Wk, Wq, u, kq, qq);

    // G = x^T x  (TN both, split-K 8x512, atomic fp32) ; then bf16 copy
    gemm128<2, 2, 2><<<dim3(8, 8, 8), blk, 0, stream>>>(
        xb, xb, (void*)Gf, nullptr, 512, 512, E_DIM, E_DIM, E_DIM, 0, 0, 0, 1.f);
    cvt_bf16<<<dim3(512), blk, 0, stream>>>(Gf, Gb);

    // T = Wk_all G  (flat M=8192; G shared) -> bf16. 512 blocks, colocated.
    gemm128x<0><<<dim3(512), blk, 0, stream>>>(
        Wkb, Gb, (void*)Tb, E_DIM, 0, E_DIM, E_DIM, E_DIM, 0, 0, 64);
    // scores_raw = T Wq_h^T. 1024 blocks (4/CU): split-K 2 x atomic fp32.
    gemm128x<2><<<dim3(1024), blk, 0, stream>>>(
        Tb, Wqb, (void*)Sc, 512, 512, E_DIM, E_DIM, E_DIM, EE, 0, 64);
    // A_h = softmax((raw + rank1)/32)
    softmax_fused<<<dim3(H_DIM * E_DIM), blk, 0, stream>>>(Sc, kq, qq, bk, bq, Ab);

    // Mcat[e][h*E+f] = (Wv_h^T A_h)[e][f]  (TN both)
    gemm128<2, 2, 0><<<dim3(8, 8, 8), blk, 0, stream>>>(
        Wvb, Ab, (void*)Mcat, nullptr, E_DIM, 0, E_DIM, E_DIM, H_DIM * E_DIM,
        EE, EE, E_DIM, 1.f);
    // zb = bv^T A ; oc = Wz zb + bz
    colsum_zb<<<dim3(4, 8, 4), blk, 0, stream>>>(Ab, bv, zb);
    gemv_oc<<<dim3(256), blk, 0, stream>>>(Wz, zb, bz, oc);

    // PT[g][e] = sum_F Wz[g][F] Mcat[e][F]  (split-K 8x1024, atomic fp32)
    gemm128x<2><<<dim3(512), blk, 0, stream>>>(
        Wzb, Mcat, (void*)PTf, 1024, 1024, H_DIM * E_DIM, H_DIM * E_DIM,
        E_DIM, 0, 0, 8);
    cvt_bf16<<<dim3(512), blk, 0, stream>>>(PTf, PTb);

    // O partials = x PT^T  (split-K 2x512 -> 2 fp32 partials; bias oc in LN)
    gemm128x<1><<<dim3(512), blk, 0, stream>>>(
        xb, PTb, (void*)Ob, 512, 512, E_DIM, E_DIM, E_DIM, 0, SE, 32);
    // LN1 = LN(O0+O1+oc)*g1+b1 + x
    ln_residual<2, true, true><<<dim3(S_DIM), blk, 0, stream>>>(
        Ob, oc, x, g1, b1, LN1b, LN1f);

    // FN partials = LN1 Wf^T  (split-K 2x512; bias bf in LN)
    gemm128x<1><<<dim3(512), blk, 0, stream>>>(
        LN1b, Wfb, (void*)FNb, 512, 512, E_DIM, E_DIM, E_DIM, 0, SE, 32);
    // out = LN(FN0+FN1+bf)*g2+b2 + LN1
    ln_residual<2, true, false><<<dim3(S_DIM), blk, 0, stream>>>(
        FNb, bfp, LN1f, g2, b2, nullptr, (float*)d_out);
}

// Round 4
// 478.648 us; speedup vs baseline: 1.1901x; 1.1901x over previous
//
#include <hip/hip_runtime.h>

#define S_DIM 4096
#define E_DIM 1024
#define H_DIM 8

typedef __bf16 bf16x8 __attribute__((ext_vector_type(8)));
typedef float  f32x4  __attribute__((ext_vector_type(4)));

// Async global->LDS, 16B per lane. LDS dest is wave-uniform base + lane*16.
__device__ __forceinline__ void async16(const __bf16* gsrc, __bf16* lbase, int lane)
{
#if __has_builtin(__builtin_amdgcn_global_load_lds)
    __builtin_amdgcn_global_load_lds(
        (const __attribute__((address_space(1))) unsigned int*)gsrc,
        (__attribute__((address_space(3))) unsigned int*)lbase, 16, 0, 0);
#else
    ((int4*)lbase)[lane] = *(const int4*)gsrc;
#endif
}

// ---------------------------------------------------------------------------
// Operand staging into LDS (bf16 sources only) for gemm128 (TN path).
// ---------------------------------------------------------------------------
template <int MODE>
__device__ __forceinline__ void stage_op(const __bf16* __restrict__ src, int ld,
                                         int mn0, int k0, __bf16* lds, int tid)
{
    if constexpr (MODE == 0) {
        const int w = tid >> 6, l = tid & 63;
        const int r8 = l >> 3, c8 = (l & 7) << 3;
#pragma unroll
        for (int i = 0; i < 4; i++) {
            const int rbase = w * 32 + i * 8;
            const __bf16* g = src + (size_t)(mn0 + rbase + r8) * ld + k0 + c8;
            async16(g, &lds[rbase * 64], l);
        }
    } else {
        const int cg = tid & 15, kg = tid >> 4;
        __bf16 h[4][8];
#pragma unroll
        for (int r = 0; r < 4; r++) {
            const __bf16* s = src + (size_t)(k0 + kg * 4 + r) * ld + mn0 + cg * 8;
            *(int4*)&h[r][0] = *(const int4*)s;
        }
        const int xr = cg & 7;
#pragma unroll
        for (int j = 0; j < 8; j++) {
            union { __bf16 q[4]; unsigned long long v; } u;
            u.q[0]=h[0][j]; u.q[1]=h[1][j]; u.q[2]=h[2][j]; u.q[3]=h[3][j];
            const int scol = cg * 8 + (j ^ xr);
            *(unsigned long long*)&lds[scol * 72 + kg * 4] = u.v;
        }
    }
}

// ---------------------------------------------------------------------------
// 128x128-tile bf16 MFMA GEMM (kept for TN-staged operands: G, Mcat).
// ---------------------------------------------------------------------------
template <int AM, int BM, int OUT>
__global__ __launch_bounds__(256) void gemm128(
    const __bf16* __restrict__ Ag, const __bf16* __restrict__ Bg,
    void* __restrict__ Cg, const float* __restrict__ biasg,
    int Klen, int kPerZ, int lda, int ldb, int ldc,
    long long sA, long long sB, long long sC, float scale)
{
    __shared__ __bf16 As[128 * 72];
    __shared__ __bf16 Bs[128 * 72];
    constexpr int SA = (AM == 2) ? 72 : 64;
    constexpr int SB = (BM == 2) ? 72 : 64;

    const int tid  = threadIdx.x;
    const int lane = tid & 63;
    const int wave = tid >> 6;
    const int t    = lane & 15;
    const int quad = lane >> 4;
    const int wm   = wave >> 1;
    const int wn   = wave & 1;
    const int m0   = blockIdx.y * 128;
    const int n0   = blockIdx.x * 128;
    const size_t zi = blockIdx.z;

    const __bf16* A = (kPerZ == 0) ? Ag + zi * sA : Ag;
    const __bf16* B = (kPerZ == 0) ? Bg + zi * sB : Bg;
    const int kbeg = kPerZ ? (int)zi * kPerZ : 0;

    int rowA[4], rowB[4];
#pragma unroll
    for (int i = 0; i < 4; i++) {
        int ra = wm * 64 + i * 16 + t;
        int rb = wn * 64 + i * 16 + t;
        rowA[i] = (AM == 2) ? (ra ^ ((ra >> 3) & 7)) : ra;
        rowB[i] = (BM == 2) ? (rb ^ ((rb >> 3) & 7)) : rb;
    }

    f32x4 acc[4][4];
#pragma unroll
    for (int i = 0; i < 4; i++)
#pragma unroll
        for (int j = 0; j < 4; j++) { f32x4 z = {0.f,0.f,0.f,0.f}; acc[i][j] = z; }

    for (int k0 = kbeg; k0 < kbeg + Klen; k0 += 64) {
        stage_op<AM>(A, lda, m0, k0, As, tid);
        stage_op<BM>(B, ldb, n0, k0, Bs, tid);
        __syncthreads();
#pragma unroll
        for (int kk = 0; kk < 2; kk++) {
            bf16x8 af[4], bfv[4];
#pragma unroll
            for (int i = 0; i < 4; i++)
                af[i] = *(const bf16x8*)(&As[rowA[i] * SA + kk*32 + quad*8]);
#pragma unroll
            for (int j = 0; j < 4; j++)
                bfv[j] = *(const bf16x8*)(&Bs[rowB[j] * SB + kk*32 + quad*8]);
#pragma unroll
            for (int i = 0; i < 4; i++)
#pragma unroll
                for (int j = 0; j < 4; j++)
                    acc[i][j] = __builtin_amdgcn_mfma_f32_16x16x32_bf16(af[i], bfv[j], acc[i][j], 0, 0, 0);
        }
        __syncthreads();
    }

#pragma unroll
    for (int i = 0; i < 4; i++) {
        const int rowb = m0 + wm*64 + i*16 + quad*4;
#pragma unroll
        for (int j = 0; j < 4; j++) {
            const int col = n0 + wn*64 + j*16 + t;
            const float bv = biasg ? biasg[col] : 0.f;
#pragma unroll
            for (int r = 0; r < 4; r++) {
                const float v = acc[i][j][r] * scale + bv;
                if constexpr (OUT == 0) {
                    __bf16* C = (__bf16*)Cg + zi * sC;
                    C[(size_t)(rowb + r) * ldc + col] = (__bf16)v;
                } else if constexpr (OUT == 1) {
                    float* C = (float*)Cg + zi * sC;
                    C[(size_t)(rowb + r) * ldc + col] = v;
                } else {
                    float* C = (float*)Cg;
                    atomicAdd(&C[(size_t)(rowb + r) * ldc + col], v);
                }
            }
        }
    }
}

// ---------------------------------------------------------------------------
// 256x128 NT-NT GEMM, m201-style subtile-pipelined phases. 512 thr = 8 waves
// (4M x 2N), wave tile 64x64, BK=64. LDS 96 KiB = 2 bufs x 3 subtiles x 16KB.
// Subtiles per K-step: alpha = wave-tile row-halves [w*64, w*64+32) (stored as
// 128 compact rows), beta = [w*64+32, w*64+64), B = 128 N-rows.
// Per K-step, two phases:
//  A: stage alpha,B(kt+1) [4 gload]; vmcnt(6); barrier; read alpha,B(kt)
//     [12 ds_read]; 16 MFMA (i=0,1) under setprio; barrier
//  B: stage beta(kt+1) [2 gload]; vmcnt(6); barrier; read beta(kt) [4 ds_read];
//     16 MFMA (i=2,3, reusing bfr regs); barrier
// vmcnt(6) proves exactly the oldest subtile(s) needed while 3 subtiles stay
// in flight (never drains mid-loop). Overwrite of buf^1 subtile S(kt+1) is
// safe: all reads of S(kt-1) completed before the end-of-phase barrier that
// precedes the stage. Tail (kt==NT-1): vmcnt(2) / vmcnt(0).
// LDS swizzle: slot s of row r holds global 16B-group s ^ (r&7) (8 slots/row
// at BK=64); staged via pre-swizzled global slot, read with same XOR ->
// fragment ds_read_b128 is 2-way (free). gload dest stays linear (rule 21).
// Grid 1D: bpz = nMt*8 blocks per K-slice; if mtpx>0, XCD-colocating decode
// (requires nMt == 8*mtpx): xcd=rr&7 owns mtpx M-tiles x 8 N-tiles.
// B head-select for block-diagonal batched B: B += (m0>>10)*sBhead.
// OUT: 0=bf16 store, 1=fp32 store at Cg+zi*sC. No atomics.
// ---------------------------------------------------------------------------
template <int OUT>
__global__ __launch_bounds__(512, 1) void gemmP(
    const __bf16* __restrict__ Ag, const __bf16* __restrict__ Bg,
    void* __restrict__ Cg, int Klen, int kPerZ,
    int lda, int ldb, int ldc, long long sBhead, long long sC,
    int nMt, int mtpx)
{
    __shared__ __bf16 sm[2 * 24576];   // buf: alpha[8192] beta[8192] B[8192]

    const int tid  = threadIdx.x;
    const int lane = tid & 63;
    const int wave = tid >> 6;
    const int wm = wave >> 1, wn = wave & 1;   // 4M x 2N
    const int t = lane & 15, q = lane >> 4;

    const int bid = blockIdx.x;
    const int bpz = nMt << 3;
    const int zi  = bid / bpz;
    const int rr  = bid - zi * bpz;
    int mt, nt;
    if (mtpx > 0) {
        const int xcd = rr & 7, s = rr >> 3;
        mt = xcd * mtpx + (s >> 3);
        nt = s & 7;
    } else {
        mt = rr >> 3;
        nt = rr & 7;
    }
    const int m0 = mt * 256;
    const int n0 = nt * 128;
    const int kbeg = zi * kPerZ;
    const int NT = Klen >> 6;                  // K-steps of 64

    const __bf16* Bp = Bg + (size_t)(m0 >> 10) * sBhead;

    // staging geometry: per subtile 128 rows x 64, 2 passes of 64 rows;
    // lane covers row (lane>>3), slot (lane&7), pre-swizzled global slot.
    const int gslot = ((lane & 7) ^ (lane >> 3)) & 7;
    const int lrow  = lane >> 3;

    // which: 0=alpha, 1=beta, 2=B
    auto stage_sub = [&](int kt, int which) {
        __bf16* base = &sm[(kt & 1) * 24576 + which * 8192 + wave * 512];
        const int k0 = kbeg + kt * 64;
#pragma unroll
        for (int p = 0; p < 2; p++) {
            const int idx = p * 64 + wave * 8 + lrow;
            int grow;
            const __bf16* src;
            int ld;
            if (which == 2) { grow = n0 + idx; src = Bp; ld = ldb; }
            else {
                grow = m0 + (((idx >> 5) << 6) | (idx & 31)) + (which ? 32 : 0);
                src = Ag; ld = lda;
            }
            async16(src + (size_t)grow * ld + k0 + gslot * 8, base + p * 4096, lane);
        }
    };

    const int fx = t & 7;                      // read-side XOR (row&7 == t&7)

    f32x4 acc[4][4];
#pragma unroll
    for (int i = 0; i < 4; i++)
#pragma unroll
        for (int j = 0; j < 4; j++) { f32x4 z = {0.f,0.f,0.f,0.f}; acc[i][j] = z; }

    // prologue: stage kt=0 subtiles in order alpha, B, beta (oldest-4 = alpha,B)
    stage_sub(0, 0); stage_sub(0, 2); stage_sub(0, 1);

    for (int kt = 0; kt < NT; ++kt) {
        const __bf16* ba = &sm[(kt & 1) * 24576];
        const __bf16* bb = ba + 8192;
        const __bf16* bB = ba + 16384;

        // ---- phase A ----
        if (kt + 1 < NT) {
            stage_sub(kt + 1, 0); stage_sub(kt + 1, 2);
            asm volatile("s_waitcnt vmcnt(6)" ::: "memory");
        } else {
            asm volatile("s_waitcnt vmcnt(2)" ::: "memory");
        }
        __builtin_amdgcn_s_barrier();
        __builtin_amdgcn_sched_barrier(0);

        bf16x8 bfr[4][2], afr[2][2];
#pragma unroll
        for (int j = 0; j < 4; j++)
#pragma unroll
            for (int kk = 0; kk < 2; kk++)
                bfr[j][kk] = *(const bf16x8*)&bB[(wn*64 + j*16 + t) * 64 + (((kk<<2)|q) ^ fx) * 8];
#pragma unroll
        for (int i = 0; i < 2; i++)
#pragma unroll
            for (int kk = 0; kk < 2; kk++)
                afr[i][kk] = *(const bf16x8*)&ba[(wm*32 + i*16 + t) * 64 + (((kk<<2)|q) ^ fx) * 8];

        __builtin_amdgcn_s_setprio(1);
#pragma unroll
        for (int i = 0; i < 2; i++)
#pragma unroll
            for (int kk = 0; kk < 2; kk++)
#pragma unroll
                for (int j = 0; j < 4; j++)
                    acc[i][j] = __builtin_amdgcn_mfma_f32_16x16x32_bf16(afr[i][kk], bfr[j][kk], acc[i][j], 0, 0, 0);
        __builtin_amdgcn_s_setprio(0);
        __builtin_amdgcn_s_barrier();
        __builtin_amdgcn_sched_barrier(0);

        // ---- phase B ----
        if (kt + 1 < NT) {
            stage_sub(kt + 1, 1);
            asm volatile("s_waitcnt vmcnt(6)" ::: "memory");
        } else {
            asm volatile("s_waitcnt vmcnt(0)" ::: "memory");
        }
        __builtin_amdgcn_s_barrier();
        __builtin_amdgcn_sched_barrier(0);

        bf16x8 afr2[2][2];
#pragma unroll
        for (int i = 0; i < 2; i++)
#pragma unroll
            for (int kk = 0; kk < 2; kk++)
                afr2[i][kk] = *(const bf16x8*)&bb[(wm*32 + i*16 + t) * 64 + (((kk<<2)|q) ^ fx) * 8];

        __builtin_amdgcn_s_setprio(1);
#pragma unroll
        for (int i = 0; i < 2; i++)
#pragma unroll
            for (int kk = 0; kk < 2; kk++)
#pragma unroll
                for (int j = 0; j < 4; j++)
                    acc[i+2][j] = __builtin_amdgcn_mfma_f32_16x16x32_bf16(afr2[i][kk], bfr[j][kk], acc[i+2][j], 0, 0, 0);
        __builtin_amdgcn_s_setprio(0);
        __builtin_amdgcn_s_barrier();
        __builtin_amdgcn_sched_barrier(0);
    }

#pragma unroll
    for (int i = 0; i < 4; i++) {
        const int rowb = m0 + wm * 64 + i * 16 + q * 4;
#pragma unroll
        for (int j = 0; j < 4; j++) {
            const int col = n0 + wn * 64 + j * 16 + t;
#pragma unroll
            for (int r = 0; r < 4; r++) {
                const float v = acc[i][j][r];
                if constexpr (OUT == 0) {
                    ((__bf16*)Cg)[(size_t)(rowb + r) * ldc + col] = (__bf16)v;
                } else {
                    float* C = (float*)Cg + (size_t)zi * sC;
                    C[(size_t)(rowb + r) * ldc + col] = v;
                }
            }
        }
    }
}

// fp32 -> bf16, 8 elems/thread, exact-size grid (n multiple of 2048).
__global__ __launch_bounds__(256) void cvt_bf16(
    const float* __restrict__ in, __bf16* __restrict__ out)
{
    const size_t i = ((size_t)blockIdx.x * 256 + threadIdx.x) * 8;
    float4 a = *(const float4*)(in + i);
    float4 b = *(const float4*)(in + i + 4);
    union { __bf16 h[8]; int4 v; } u;
    u.h[0]=(__bf16)a.x; u.h[1]=(__bf16)a.y; u.h[2]=(__bf16)a.z; u.h[3]=(__bf16)a.w;
    u.h[4]=(__bf16)b.x; u.h[5]=(__bf16)b.y; u.h[6]=(__bf16)b.z; u.h[7]=(__bf16)b.w;
    *(int4*)(out + i) = u.v;
}

// sum of 8 fp32 partials (stride EE) -> bf16. grid 512 x 256 thr.
__global__ __launch_bounds__(256) void sum8_cvt(
    const float* __restrict__ P, __bf16* __restrict__ out)
{
    const size_t EE = (size_t)E_DIM * E_DIM;
    const size_t i = ((size_t)blockIdx.x * 256 + threadIdx.x) * 8;
    float4 a = {0.f,0.f,0.f,0.f}, b = {0.f,0.f,0.f,0.f};
#pragma unroll
    for (int p = 0; p < 8; p++) {
        float4 x = *(const float4*)(P + p*EE + i);
        float4 y = *(const float4*)(P + p*EE + i + 4);
        a.x+=x.x; a.y+=x.y; a.z+=x.z; a.w+=x.w;
        b.x+=y.x; b.y+=y.y; b.z+=y.z; b.w+=y.w;
    }
    union { __bf16 h[8]; int4 v; } u;
    u.h[0]=(__bf16)a.x; u.h[1]=(__bf16)a.y; u.h[2]=(__bf16)a.z; u.h[3]=(__bf16)a.w;
    u.h[4]=(__bf16)b.x; u.h[5]=(__bf16)b.y; u.h[6]=(__bf16)b.z; u.h[7]=(__bf16)b.w;
    *(int4*)(out + i) = u.v;
}

// u[e] = sum_s x[s][e].  64 blocks x 64 rows; u pre-zeroed.
__global__ __launch_bounds__(256) void colsum_u(const float* __restrict__ x, float* __restrict__ u)
{
    const int c = threadIdx.x * 4;
    float4 a = {0.f,0.f,0.f,0.f};
    const int r0 = blockIdx.x * 64;
    for (int r = 0; r < 64; r++) {
        float4 v = *(const float4*)(x + (size_t)(r0 + r) * E_DIM + c);
        a.x += v.x; a.y += v.y; a.z += v.z; a.w += v.w;
    }
    atomicAdd(&u[c+0], a.x); atomicAdd(&u[c+1], a.y);
    atomicAdd(&u[c+2], a.z); atomicAdd(&u[c+3], a.w);
}

// kq[r] = Wk[r,:]·u ; qq[r] = Wq[r,:]·u  (r = h*E+j, 8192 rows each)
__global__ __launch_bounds__(256) void gemv_u(
    const float* __restrict__ Wk, const float* __restrict__ Wq,
    const float* __restrict__ u, float* __restrict__ kq, float* __restrict__ qq)
{
    const int gw = blockIdx.x * 4 + (threadIdx.x >> 6);
    const int lane = threadIdx.x & 63;
    const float* W = (gw < 8192) ? Wk + (size_t)gw * E_DIM
                                 : Wq + (size_t)(gw - 8192) * E_DIM;
    float s = 0.f;
#pragma unroll
    for (int i = 0; i < 4; i++) {
        float4 w = *(const float4*)(W + lane*16 + i*4);
        float4 z = *(const float4*)(u + lane*16 + i*4);
        s += w.x*z.x + w.y*z.y + w.z*z.z + w.w*z.w;
    }
#pragma unroll
    for (int o = 32; o > 0; o >>= 1) s += __shfl_down(s, o);
    if (lane == 0) { if (gw < 8192) kq[gw] = s; else qq[gw - 8192] = s; }
}

// zb[h*E+f] = sum_o bv[h][o] * A[h][o][f]; zb pre-zeroed. grid (4,8,4)
__global__ __launch_bounds__(256) void colsum_zb(
    const __bf16* __restrict__ Ab, const float* __restrict__ bv, float* __restrict__ zb)
{
    const int h = blockIdx.y;
    const int f = blockIdx.x * 256 + threadIdx.x;
    const int o0 = blockIdx.z * 256;
    const __bf16* A = Ab + (size_t)h * E_DIM * E_DIM + (size_t)o0 * E_DIM + f;
    const float* bvh = bv + h * E_DIM + o0;
    float s = 0.f;
    for (int o = 0; o < 256; o++) s += bvh[o] * (float)A[(size_t)o * E_DIM];
    atomicAdd(&zb[h * E_DIM + f], s);
}

// oc[g] = zb·Wz[g,:] + bz[g]   (K=8192, one wave per row)
__global__ __launch_bounds__(256) void gemv_oc(
    const float* __restrict__ Wz, const float* __restrict__ zb,
    const float* __restrict__ bz, float* __restrict__ oc)
{
    const int gw = blockIdx.x * 4 + (threadIdx.x >> 6);
    const int lane = threadIdx.x & 63;
    const float* W = Wz + (size_t)gw * (H_DIM * E_DIM);
    float s = 0.f;
#pragma unroll
    for (int i = 0; i < 32; i++) {
        float4 w = *(const float4*)(W + i*256 + lane*4);
        float4 z = *(const float4*)(zb + i*256 + lane*4);
        s += w.x*z.x + w.y*z.y + w.z*z.z + w.w*z.w;
    }
#pragma unroll
    for (int o = 32; o > 0; o >>= 1) s += __shfl_down(s, o);
    if (lane == 0) oc[gw] = s + bz[gw];
}

// softmax over f with fused rank-1 bias terms and 1/sqrt(E) scale.
__global__ __launch_bounds__(256) void softmax_fused(
    const float* __restrict__ Sc, const float* __restrict__ kq,
    const float* __restrict__ qq, const float* __restrict__ bk,
    const float* __restrict__ bq, __bf16* __restrict__ Aout)
{
    __shared__ float red[4];
    const int row = blockIdx.x;
    const int h = row >> 10;
    const int tid = threadIdx.x, lane = tid & 63, wave = tid >> 6;
    const float kqj = kq[row], bkj = bk[row];
    const float cst = (float)S_DIM * bkj;

    float4 v = ((const float4*)(Sc + (size_t)row * E_DIM))[tid];
    const int c = tid * 4;
    float4 qv = *(const float4*)(qq + (h << 10) + c);
    float4 bv = *(const float4*)(bq + (h << 10) + c);
    v.x = (v.x + kqj*bv.x + bkj*qv.x + cst*bv.x) * 0.03125f;
    v.y = (v.y + kqj*bv.y + bkj*qv.y + cst*bv.y) * 0.03125f;
    v.z = (v.z + kqj*bv.z + bkj*qv.z + cst*bv.z) * 0.03125f;
    v.w = (v.w + kqj*bv.w + bkj*qv.w + cst*bv.w) * 0.03125f;

    float m = fmaxf(fmaxf(v.x, v.y), fmaxf(v.z, v.w));
#pragma unroll
    for (int o = 32; o > 0; o >>= 1) m = fmaxf(m, __shfl_down(m, o));
    if (lane == 0) red[wave] = m;
    __syncthreads();
    m = fmaxf(fmaxf(red[0], red[1]), fmaxf(red[2], red[3]));
    __syncthreads();

    const float e0 = __expf(v.x - m), e1 = __expf(v.y - m);
    const float e2 = __expf(v.z - m), e3 = __expf(v.w - m);
    float s = e0 + e1 + e2 + e3;
#pragma unroll
    for (int o = 32; o > 0; o >>= 1) s += __shfl_down(s, o);
    if (lane == 0) red[wave] = s;
    __syncthreads();
    s = red[0] + red[1] + red[2] + red[3];
    const float inv = 1.f / s;

    __bf16* out = Aout + (size_t)row * E_DIM + c;
    out[0] = (__bf16)(e0*inv); out[1] = (__bf16)(e1*inv);
    out[2] = (__bf16)(e2*inv); out[3] = (__bf16)(e3*inv);
}

// LN + residual. X = sum of NPART fp32 partials (stride S*E) + optional
// per-column bias cb. out = LN(X)*g + b + resid.
template <int NPART, bool CB, bool WRITE_BF16>
__global__ __launch_bounds__(256) void ln_residual(
    const float* __restrict__ X, const float* __restrict__ cb,
    const float* __restrict__ resid,
    const float* __restrict__ g, const float* __restrict__ b,
    __bf16* __restrict__ outB, float* __restrict__ outF)
{
    __shared__ float redS[4], redQ[4];
    const int row = blockIdx.x;
    const int tid = threadIdx.x, lane = tid & 63, wave = tid >> 6;
    const size_t SE = (size_t)S_DIM * E_DIM;

    float4 v = ((const float4*)(X + (size_t)row * E_DIM))[tid];
#pragma unroll
    for (int p = 1; p < NPART; ++p) {
        float4 v1 = ((const float4*)(X + (size_t)p * SE + (size_t)row * E_DIM))[tid];
        v.x += v1.x; v.y += v1.y; v.z += v1.z; v.w += v1.w;
    }
    if constexpr (CB) {
        float4 cv = ((const float4*)cb)[tid];
        v.x += cv.x; v.y += cv.y; v.z += cv.z; v.w += cv.w;
    }
    float s = v.x + v.y + v.z + v.w;
    float q = v.x*v.x + v.y*v.y + v.z*v.z + v.w*v.w;
#pragma unroll
    for (int o = 32; o > 0; o >>= 1) { s += __shfl_down(s, o); q += __shfl_down(q, o); }
    if (lane == 0) { redS[wave] = s; redQ[wave] = q; }
    __syncthreads();
    s = redS[0]+redS[1]+redS[2]+redS[3];
    q = redQ[0]+redQ[1]+redQ[2]+redQ[3];

    const float mean = s * (1.f / E_DIM);
    const float var  = q * (1.f / E_DIM) - mean * mean;
    const float rstd = rsqrtf(var + 1e-5f);

    const int c0 = tid * 4;
    float4 rv = ((const float4*)(resid + (size_t)row * E_DIM))[tid];
    const float res[4] = {rv.x, rv.y, rv.z, rv.w};
    const float* vp = &v.x;
#pragma unroll
    for (int i = 0; i < 4; i++) {
        const float o = (vp[i] - mean) * rstd * g[c0+i] + b[c0+i] + res[i];
        outF[(size_t)row * E_DIM + c0 + i] = o;
        if constexpr (WRITE_BF16) outB[(size_t)row * E_DIM + c0 + i] = (__bf16)o;
    }
}

// ---------------------------------------------------------------------------
extern "C" void kernel_launch(void* const* d_in, const int* in_sizes, int n_in,
                              void* d_out, int out_size, void* d_ws, size_t ws_size,
                              hipStream_t stream)
{
    const float* x   = (const float*)d_in[0];
    const float* Wq  = (const float*)d_in[1];
    const float* bq  = (const float*)d_in[2];
    const float* Wk  = (const float*)d_in[3];
    const float* bk  = (const float*)d_in[4];
    const float* Wv  = (const float*)d_in[5];
    const float* bv  = (const float*)d_in[6];
    const float* Wz  = (const float*)d_in[7];
    const float* bz  = (const float*)d_in[8];
    const float* g1  = (const float*)d_in[9];
    const float* b1  = (const float*)d_in[10];
    const float* Wf  = (const float*)d_in[11];
    const float* bfp = (const float*)d_in[12];
    const float* g2  = (const float*)d_in[13];
    const float* b2  = (const float*)d_in[14];

    char* ws = (char*)d_ws;
    const long long EE = (long long)E_DIM * E_DIM;
    const long long SE = (long long)S_DIM * E_DIM;
    const size_t MB = 1024ull * 1024ull;

    // bf16 operand copies
    __bf16* xb   = (__bf16*)(ws);             //  8 MiB
    __bf16* Wqb  = (__bf16*)(ws +   8*MB);    // 16 MiB
    __bf16* Wkb  = (__bf16*)(ws +  24*MB);    // 16 MiB
    __bf16* Wvb  = (__bf16*)(ws +  40*MB);    // 16 MiB
    __bf16* Wzb  = (__bf16*)(ws +  56*MB);    // 16 MiB
    __bf16* Wfb  = (__bf16*)(ws +  72*MB);    //  2 MiB
    float*  Gf   = (float*) (ws +  74*MB);    //  4 MiB
    __bf16* Gb   = (__bf16*)(ws +  78*MB);    //  2 MiB
    __bf16* PTb  = (__bf16*)(ws +  84*MB);    //  2 MiB
    float*  u    = (float*) (ws +  86*MB);
    float*  kq   = (float*) (ws +  86*MB +  65536);
    float*  qq   = (float*) (ws +  86*MB + 131072);
    float*  zb   = (float*) (ws +  86*MB + 196608);
    float*  oc   = (float*) (ws +  86*MB + 262144);
    __bf16* LN1b = (__bf16*)(ws +  87*MB);    //  8 MiB
    float*  LN1f = (float*) (ws +  95*MB);    // 16 MiB
    __bf16* Tb   = (__bf16*)(ws + 111*MB);    // 16 MiB  (dead after scores)
    float*  Sc   = (float*) (ws + 127*MB);    // 32 MiB  (dead after softmax)
    __bf16* Ab   = (__bf16*)(ws + 159*MB);    // 16 MiB  (dead after Mcat/zb)
    __bf16* Mcat = (__bf16*)(ws + 175*MB);    // 16 MiB  (dead after PT; end 191)
    float*  PTp  = (float*) (ws + 111*MB);    // 32 MiB  8 partials (over Tb+Sc lo; Tb/Sc dead)
    float*  Ob   = (float*) (ws + 111*MB);    // 32 MiB  2 partials (PTp dead after sum8)
    float*  FNb  = (float*) (ws + 111*MB);    // 32 MiB  2 partials (Ob dead after LN1)

    dim3 blk(256);
    dim3 blk5(512);

    // zero accumulators (ws is 0xAA-poisoned)
    hipMemsetAsync(Gf,  0, 4*MB, stream);
    hipMemsetAsync(u,   0, E_DIM*4, stream);
    hipMemsetAsync(zb,  0, H_DIM*E_DIM*4, stream);

    // fp32 -> bf16 operand conversions
    cvt_bf16<<<dim3(2048), blk, 0, stream>>>(x,  xb);
    cvt_bf16<<<dim3(4096), blk, 0, stream>>>(Wq, Wqb);
    cvt_bf16<<<dim3(4096), blk, 0, stream>>>(Wk, Wkb);
    cvt_bf16<<<dim3(4096), blk, 0, stream>>>(Wv, Wvb);
    cvt_bf16<<<dim3(4096), blk, 0, stream>>>(Wz, Wzb);
    cvt_bf16<<<dim3(512),  blk, 0, stream>>>(Wf, Wfb);

    // u = colsum(x); kq = Wk u; qq = Wq u  (fp32 exact)
    colsum_u<<<dim3(64), blk, 0, stream>>>(x, u);
    gemv_u<<<dim3(4096), blk, 0, stream>>>(Wk, Wq, u, kq, qq);

    // G = x^T x  (TN both, split-K 8x512, atomic fp32) ; then bf16 copy
    gemm128<2, 2, 2><<<dim3(8, 8, 8), blk, 0, stream>>>(
        xb, xb, (void*)Gf, nullptr, 512, 512, E_DIM, E_DIM, E_DIM, 0, 0, 0, 1.f);
    cvt_bf16<<<dim3(512), blk, 0, stream>>>(Gf, Gb);

    // T = Wk_all G  (flat M=8192; G shared, symmetric) -> bf16. 256 blocks.
    gemmP<0><<<dim3(256), blk5, 0, stream>>>(
        Wkb, Gb, (void*)Tb, 1024, 0, E_DIM, E_DIM, E_DIM, 0, 0, 32, 4);
    // scores_raw = T Wq_h^T  (per-head B via m0>>10) -> fp32. 256 blocks.
    gemmP<1><<<dim3(256), blk5, 0, stream>>>(
        Tb, Wqb, (void*)Sc, 1024, 0, E_DIM, E_DIM, E_DIM, EE, 0, 32, 4);
    // A_h = softmax((raw + rank1)/32)
    softmax_fused<<<dim3(H_DIM * E_DIM), blk, 0, stream>>>(Sc, kq, qq, bk, bq, Ab);

    // Mcat[e][h*E+f] = (Wv_h^T A_h)[e][f]  (TN both)
    gemm128<2, 2, 0><<<dim3(8, 8, 8), blk, 0, stream>>>(
        Wvb, Ab, (void*)Mcat, nullptr, E_DIM, 0, E_DIM, E_DIM, H_DIM * E_DIM,
        EE, EE, E_DIM, 1.f);
    // zb = bv^T A ; oc = Wz zb + bz
    colsum_zb<<<dim3(4, 8, 4), blk, 0, stream>>>(Ab, bv, zb);
    gemv_oc<<<dim3(256), blk, 0, stream>>>(Wz, zb, bz, oc);

    // PT[g][e] = sum_F Wz[g][F] Mcat[e][F]  split-K 8x1024 stored partials
    gemmP<1><<<dim3(256), blk5, 0, stream>>>(
        Wzb, Mcat, (void*)PTp, 1024, 1024, H_DIM * E_DIM, H_DIM * E_DIM,
        E_DIM, 0, EE, 4, 0);
    sum8_cvt<<<dim3(512), blk, 0, stream>>>(PTp, PTb);

    // O partials = x PT^T  (split-K 2x512 -> 2 fp32 partials; bias oc in LN)
    gemmP<1><<<dim3(256), blk5, 0, stream>>>(
        xb, PTb, (void*)Ob, 512, 512, E_DIM, E_DIM, E_DIM, 0, SE, 16, 2);
    // LN1 = LN(O0+O1+oc)*g1+b1 + x
    ln_residual<2, true, true><<<dim3(S_DIM), blk, 0, stream>>>(
        Ob, oc, x, g1, b1, LN1b, LN1f);

    // FN partials = LN1 Wf^T  (split-K 2x512; bias bf in LN)
    gemmP<1><<<dim3(256), blk5, 0, stream>>>(
        LN1b, Wfb, (void*)FNb, 512, 512, E_DIM, E_DIM, E_DIM, 0, SE, 16, 2);
    // out = LN(FN0+FN1+bf)*g2+b2 + LN1
    ln_residual<2, true, false><<<dim3(S_DIM), blk, 0, stream>>>(
        FNb, bfp, LN1f, g2, b2, nullptr, (float*)d_out);
}

// Round 6
// 453.633 us; speedup vs baseline: 1.2558x; 1.0551x over previous
//
#include <hip/hip_runtime.h>

#define S_DIM 4096
#define E_DIM 1024
#define H_DIM 8

typedef __bf16 bf16x8 __attribute__((ext_vector_type(8)));
typedef float  f32x4  __attribute__((ext_vector_type(4)));

// Async global->LDS, 16B per lane. LDS dest is wave-uniform base + lane*16.
__device__ __forceinline__ void async16(const __bf16* gsrc, __bf16* lbase, int lane)
{
#if __has_builtin(__builtin_amdgcn_global_load_lds)
    __builtin_amdgcn_global_load_lds(
        (const __attribute__((address_space(1))) unsigned int*)gsrc,
        (__attribute__((address_space(3))) unsigned int*)lbase, 16, 0, 0);
#else
    ((int4*)lbase)[lane] = *(const int4*)gsrc;
#endif
}

// ---------------------------------------------------------------------------
// 256x128 NT-NT GEMM, subtile-pipelined phases (structure verified R4).
// 512 thr = 8 waves (4M x 2N), wave tile 64x64, BK=64. LDS 96 KiB =
// 2 bufs x 3 subtiles x 16KB. Per K-step two phases:
//  A: stage alpha,B(kt+1) [4 gload]; vmcnt(6); barrier; read alpha,B(kt)
//     [12 ds_read]; 16 MFMA under setprio; barrier
//  B: stage beta(kt+1) [2 gload]; vmcnt(6); barrier; read beta(kt);
//     16 MFMA; barrier
// vmcnt(6) proves exactly the oldest subtiles while 3 stay in flight.
// LDS XOR swizzle: slot s of row r holds global 16B-group s ^ (r&7);
// pre-swizzled global source slot, same XOR on read (rule 21).
// Grid 1D: bpz = nMt*8 blocks per K-slice; mtpx>0 -> XCD-colocating decode
// (requires nMt == 8*mtpx). Operand addressing modes:
//  AM/BM = 0: plain      addr = P + row*ld + k
//  AM/BM = 1: M-head     addr = P + (m0>>10)*s + (row&1023 for A)*ld + k
//  AM/BM = 2: K-head     addr = P + (k>>10)*s + row*ld + (k&1023)
// (mode 1 on B keeps full row = n0+idx; head comes from m0.)
// OUT: 0=bf16 store, 1=fp32 store at Cg+zi*sC. No atomics.
// ---------------------------------------------------------------------------
template <int OUT, int AM, int BM>
__global__ __launch_bounds__(512, 1) void gemmP(
    const __bf16* __restrict__ Ag, const __bf16* __restrict__ Bg,
    void* __restrict__ Cg, int Klen, int kPerZ,
    int lda, int ldb, int ldc, long long sA, long long sB, long long sC,
    int nMt, int mtpx)
{
    __shared__ __bf16 sm[2 * 24576];   // buf: alpha[8192] beta[8192] B[8192]

    const int tid  = threadIdx.x;
    const int lane = tid & 63;
    const int wave = tid >> 6;
    const int wm = wave >> 1, wn = wave & 1;   // 4M x 2N
    const int t = lane & 15, q = lane >> 4;

    const int bid = blockIdx.x;
    const int bpz = nMt << 3;
    const int zi  = bid / bpz;
    const int rr  = bid - zi * bpz;
    int mt, nt;
    if (mtpx > 0) {
        const int xcd = rr & 7, s = rr >> 3;
        mt = xcd * mtpx + (s >> 3);
        nt = s & 7;
    } else {
        mt = rr >> 3;
        nt = rr & 7;
    }
    const int m0 = mt * 256;
    const int n0 = nt * 128;
    const int kbeg = zi * kPerZ;
    const int NT = Klen >> 6;                  // K-steps of 64

    // staging: per subtile 128 rows x 64; lane covers row (lane>>3),
    // slot (lane&7), pre-swizzled global slot.
    const int gslot = ((lane & 7) ^ (lane >> 3)) & 7;
    const int lrow  = lane >> 3;

    // which: 0=alpha (A rows [w*64,w*64+32)), 1=beta, 2=B
    auto stage_sub = [&](int kt, int which) {
        __bf16* base = &sm[(kt & 1) * 24576 + which * 8192 + wave * 512];
        const int kk = kbeg + kt * 64;
#pragma unroll
        for (int p = 0; p < 2; p++) {
            const int idx = p * 64 + wave * 8 + lrow;
            const __bf16* g;
            if (which == 2) {
                const int grow = n0 + idx;
                if constexpr (BM == 1)
                    g = Bg + (size_t)(m0 >> 10) * sB + (size_t)grow * ldb + kk + gslot * 8;
                else if constexpr (BM == 2)
                    g = Bg + (size_t)(kk >> 10) * sB + (size_t)grow * ldb + (kk & 1023) + gslot * 8;
                else
                    g = Bg + (size_t)grow * ldb + kk + gslot * 8;
            } else {
                const int grow = m0 + (((idx >> 5) << 6) | (idx & 31)) + (which ? 32 : 0);
                if constexpr (AM == 1)
                    g = Ag + (size_t)(m0 >> 10) * sA + (size_t)(grow & 1023) * lda + kk + gslot * 8;
                else if constexpr (AM == 2)
                    g = Ag + (size_t)(kk >> 10) * sA + (size_t)grow * lda + (kk & 1023) + gslot * 8;
                else
                    g = Ag + (size_t)grow * lda + kk + gslot * 8;
            }
            async16(g, base + p * 4096, lane);
        }
    };

    const int fx = t & 7;                      // read-side XOR (row&7 == t&7)

    f32x4 acc[4][4];
#pragma unroll
    for (int i = 0; i < 4; i++)
#pragma unroll
        for (int j = 0; j < 4; j++) { f32x4 z = {0.f,0.f,0.f,0.f}; acc[i][j] = z; }

    // prologue: stage kt=0 subtiles in order alpha, B, beta (oldest-4 = alpha,B)
    stage_sub(0, 0); stage_sub(0, 2); stage_sub(0, 1);

    for (int kt = 0; kt < NT; ++kt) {
        const __bf16* ba = &sm[(kt & 1) * 24576];
        const __bf16* bb = ba + 8192;
        const __bf16* bB = ba + 16384;

        // ---- phase A ----
        if (kt + 1 < NT) {
            stage_sub(kt + 1, 0); stage_sub(kt + 1, 2);
            asm volatile("s_waitcnt vmcnt(6)" ::: "memory");
        } else {
            asm volatile("s_waitcnt vmcnt(2)" ::: "memory");
        }
        __builtin_amdgcn_s_barrier();
        __builtin_amdgcn_sched_barrier(0);

        bf16x8 bfr[4][2], afr[2][2];
#pragma unroll
        for (int j = 0; j < 4; j++)
#pragma unroll
            for (int kk = 0; kk < 2; kk++)
                bfr[j][kk] = *(const bf16x8*)&bB[(wn*64 + j*16 + t) * 64 + (((kk<<2)|q) ^ fx) * 8];
#pragma unroll
        for (int i = 0; i < 2; i++)
#pragma unroll
            for (int kk = 0; kk < 2; kk++)
                afr[i][kk] = *(const bf16x8*)&ba[(wm*32 + i*16 + t) * 64 + (((kk<<2)|q) ^ fx) * 8];

        __builtin_amdgcn_s_setprio(1);
#pragma unroll
        for (int i = 0; i < 2; i++)
#pragma unroll
            for (int kk = 0; kk < 2; kk++)
#pragma unroll
                for (int j = 0; j < 4; j++)
                    acc[i][j] = __builtin_amdgcn_mfma_f32_16x16x32_bf16(afr[i][kk], bfr[j][kk], acc[i][j], 0, 0, 0);
        __builtin_amdgcn_s_setprio(0);
        __builtin_amdgcn_s_barrier();
        __builtin_amdgcn_sched_barrier(0);

        // ---- phase B ----
        if (kt + 1 < NT) {
            stage_sub(kt + 1, 1);
            asm volatile("s_waitcnt vmcnt(6)" ::: "memory");
        } else {
            asm volatile("s_waitcnt vmcnt(0)" ::: "memory");
        }
        __builtin_amdgcn_s_barrier();
        __builtin_amdgcn_sched_barrier(0);

        bf16x8 afr2[2][2];
#pragma unroll
        for (int i = 0; i < 2; i++)
#pragma unroll
            for (int kk = 0; kk < 2; kk++)
                afr2[i][kk] = *(const bf16x8*)&bb[(wm*32 + i*16 + t) * 64 + (((kk<<2)|q) ^ fx) * 8];

        __builtin_amdgcn_s_setprio(1);
#pragma unroll
        for (int i = 0; i < 2; i++)
#pragma unroll
            for (int kk = 0; kk < 2; kk++)
#pragma unroll
                for (int j = 0; j < 4; j++)
                    acc[i+2][j] = __builtin_amdgcn_mfma_f32_16x16x32_bf16(afr2[i][kk], bfr[j][kk], acc[i+2][j], 0, 0, 0);
        __builtin_amdgcn_s_setprio(0);
        __builtin_amdgcn_s_barrier();
        __builtin_amdgcn_sched_barrier(0);
    }

#pragma unroll
    for (int i = 0; i < 4; i++) {
        const int rowb = m0 + wm * 64 + i * 16 + q * 4;
#pragma unroll
        for (int j = 0; j < 4; j++) {
            const int col = n0 + wn * 64 + j * 16 + t;
#pragma unroll
            for (int r = 0; r < 4; r++) {
                const float v = acc[i][j][r];
                if constexpr (OUT == 0) {
                    ((__bf16*)Cg)[(size_t)(rowb + r) * ldc + col] = (__bf16)v;
                } else {
                    float* C = (float*)Cg + (size_t)zi * sC;
                    C[(size_t)(rowb + r) * ldc + col] = v;
                }
            }
        }
    }
}

// ---------------------------------------------------------------------------
// Transpose fp32 [R][C] -> bf16 outT [C][R]; optionally also bf16 outN [R][C].
// R,C multiples of 64. blockIdx.z batches (square head blocks: offset z*R*C
// for in, outT, outN alike). LDS 64x65 fp32 tile; 2-way conflicts only.
// ---------------------------------------------------------------------------
template <bool WN>
__global__ __launch_bounds__(256) void trans_cvt(
    const float* __restrict__ in, __bf16* __restrict__ outT,
    __bf16* __restrict__ outN, int R, int C)
{
    __shared__ float t[64][65];
    const size_t base = (size_t)blockIdx.z * R * C;
    const int r0 = blockIdx.y * 64, c0 = blockIdx.x * 64;
    const int tid = threadIdx.x;
    const int r = tid >> 2;
#pragma unroll
    for (int i = 0; i < 4; i++) {
        const int j = (tid & 3) + i * 4;            // float4 chunk 0..15
        float4 v = *(const float4*)(in + base + (size_t)(r0 + r) * C + c0 + j * 4);
        t[r][j*4+0] = v.x; t[r][j*4+1] = v.y; t[r][j*4+2] = v.z; t[r][j*4+3] = v.w;
        if constexpr (WN) {
            union { __bf16 h[4]; unsigned long long q; } u;
            u.h[0]=(__bf16)v.x; u.h[1]=(__bf16)v.y; u.h[2]=(__bf16)v.z; u.h[3]=(__bf16)v.w;
            *(unsigned long long*)(outN + base + (size_t)(r0 + r) * C + c0 + j * 4) = u.q;
        }
    }
    __syncthreads();
#pragma unroll
    for (int i = 0; i < 2; i++) {
        const int idx = tid + 256 * i;              // 0..511
        const int c = idx >> 3, h8 = idx & 7;
        union { __bf16 h[8]; int4 q; } u;
#pragma unroll
        for (int k = 0; k < 8; k++) u.h[k] = (__bf16)t[h8*8+k][c];
        *(int4*)(outT + base + (size_t)(c0 + c) * R + r0 + h8 * 8) = u.q;
    }
}

// fp32 -> bf16, 8 elems/thread, exact-size grid (n multiple of 2048).
__global__ __launch_bounds__(256) void cvt_bf16(
    const float* __restrict__ in, __bf16* __restrict__ out)
{
    const size_t i = ((size_t)blockIdx.x * 256 + threadIdx.x) * 8;
    float4 a = *(const float4*)(in + i);
    float4 b = *(const float4*)(in + i + 4);
    union { __bf16 h[8]; int4 v; } u;
    u.h[0]=(__bf16)a.x; u.h[1]=(__bf16)a.y; u.h[2]=(__bf16)a.z; u.h[3]=(__bf16)a.w;
    u.h[4]=(__bf16)b.x; u.h[5]=(__bf16)b.y; u.h[6]=(__bf16)b.z; u.h[7]=(__bf16)b.w;
    *(int4*)(out + i) = u.v;
}

// sum of 8 fp32 partials (stride EE = 1M elems) -> bf16. grid 512 x 256 thr.
__global__ __launch_bounds__(256) void sum8_cvt(
    const float* __restrict__ P, __bf16* __restrict__ out)
{
    const size_t EE = (size_t)E_DIM * E_DIM;
    const size_t i = ((size_t)blockIdx.x * 256 + threadIdx.x) * 8;
    float4 a = {0.f,0.f,0.f,0.f}, b = {0.f,0.f,0.f,0.f};
#pragma unroll
    for (int p = 0; p < 8; p++) {
        float4 x = *(const float4*)(P + p*EE + i);
        float4 y = *(const float4*)(P + p*EE + i + 4);
        a.x+=x.x; a.y+=x.y; a.z+=x.z; a.w+=x.w;
        b.x+=y.x; b.y+=y.y; b.z+=y.z; b.w+=y.w;
    }
    union { __bf16 h[8]; int4 v; } u;
    u.h[0]=(__bf16)a.x; u.h[1]=(__bf16)a.y; u.h[2]=(__bf16)a.z; u.h[3]=(__bf16)a.w;
    u.h[4]=(__bf16)b.x; u.h[5]=(__bf16)b.y; u.h[6]=(__bf16)b.z; u.h[7]=(__bf16)b.w;
    *(int4*)(out + i) = u.v;
}

// u[e] = sum_s x[s][e].  64 blocks x 64 rows; u pre-zeroed.
__global__ __launch_bounds__(256) void colsum_u(const float* __restrict__ x, float* __restrict__ u)
{
    const int c = threadIdx.x * 4;
    float4 a = {0.f,0.f,0.f,0.f};
    const int r0 = blockIdx.x * 64;
    for (int r = 0; r < 64; r++) {
        float4 v = *(const float4*)(x + (size_t)(r0 + r) * E_DIM + c);
        a.x += v.x; a.y += v.y; a.z += v.z; a.w += v.w;
    }
    atomicAdd(&u[c+0], a.x); atomicAdd(&u[c+1], a.y);
    atomicAdd(&u[c+2], a.z); atomicAdd(&u[c+3], a.w);
}

// kq[r] = Wk[r,:]·u ; qq[r] = Wq[r,:]·u  (r = h*E+j, 8192 rows each)
__global__ __launch_bounds__(256) void gemv_u(
    const float* __restrict__ Wk, const float* __restrict__ Wq,
    const float* __restrict__ u, float* __restrict__ kq, float* __restrict__ qq)
{
    const int gw = blockIdx.x * 4 + (threadIdx.x >> 6);
    const int lane = threadIdx.x & 63;
    const float* W = (gw < 8192) ? Wk + (size_t)gw * E_DIM
                                 : Wq + (size_t)(gw - 8192) * E_DIM;
    float s = 0.f;
#pragma unroll
    for (int i = 0; i < 4; i++) {
        float4 w = *(const float4*)(W + lane*16 + i*4);
        float4 z = *(const float4*)(u + lane*16 + i*4);
        s += w.x*z.x + w.y*z.y + w.z*z.z + w.w*z.w;
    }
#pragma unroll
    for (int o = 32; o > 0; o >>= 1) s += __shfl_down(s, o);
    if (lane == 0) { if (gw < 8192) kq[gw] = s; else qq[gw - 8192] = s; }
}

// zb[h*E+f] = sum_o bv[h][o] * A[h][o][f]; zb pre-zeroed. grid (4,8,4)
__global__ __launch_bounds__(256) void colsum_zb(
    const __bf16* __restrict__ Ab, const float* __restrict__ bv, float* __restrict__ zb)
{
    const int h = blockIdx.y;
    const int f = blockIdx.x * 256 + threadIdx.x;
    const int o0 = blockIdx.z * 256;
    const __bf16* A = Ab + (size_t)h * E_DIM * E_DIM + (size_t)o0 * E_DIM + f;
    const float* bvh = bv + h * E_DIM + o0;
    float s = 0.f;
    for (int o = 0; o < 256; o++) s += bvh[o] * (float)A[(size_t)o * E_DIM];
    atomicAdd(&zb[h * E_DIM + f], s);
}

// oc[g] = zb·Wz[g,:] + bz[g]   (K=8192, one wave per row)
__global__ __launch_bounds__(256) void gemv_oc(
    const float* __restrict__ Wz, const float* __restrict__ zb,
    const float* __restrict__ bz, float* __restrict__ oc)
{
    const int gw = blockIdx.x * 4 + (threadIdx.x >> 6);
    const int lane = threadIdx.x & 63;
    const float* W = Wz + (size_t)gw * (H_DIM * E_DIM);
    float s = 0.f;
#pragma unroll
    for (int i = 0; i < 32; i++) {
        float4 w = *(const float4*)(W + i*256 + lane*4);
        float4 z = *(const float4*)(zb + i*256 + lane*4);
        s += w.x*z.x + w.y*z.y + w.z*z.z + w.w*z.w;
    }
#pragma unroll
    for (int o = 32; o > 0; o >>= 1) s += __shfl_down(s, o);
    if (lane == 0) oc[gw] = s + bz[gw];
}

// softmax over f with fused rank-1 bias terms and 1/sqrt(E) scale.
__global__ __launch_bounds__(256) void softmax_fused(
    const float* __restrict__ Sc, const float* __restrict__ kq,
    const float* __restrict__ qq, const float* __restrict__ bk,
    const float* __restrict__ bq, __bf16* __restrict__ Aout)
{
    __shared__ float red[4];
    const int row = blockIdx.x;
    const int h = row >> 10;
    const int tid = threadIdx.x, lane = tid & 63, wave = tid >> 6;
    const float kqj = kq[row], bkj = bk[row];
    const float cst = (float)S_DIM * bkj;

    float4 v = ((const float4*)(Sc + (size_t)row * E_DIM))[tid];
    const int c = tid * 4;
    float4 qv = *(const float4*)(qq + (h << 10) + c);
    float4 bv = *(const float4*)(bq + (h << 10) + c);
    v.x = (v.x + kqj*bv.x + bkj*qv.x + cst*bv.x) * 0.03125f;
    v.y = (v.y + kqj*bv.y + bkj*qv.y + cst*bv.y) * 0.03125f;
    v.z = (v.z + kqj*bv.z + bkj*qv.z + cst*bv.z) * 0.03125f;
    v.w = (v.w + kqj*bv.w + bkj*qv.w + cst*bv.w) * 0.03125f;

    float m = fmaxf(fmaxf(v.x, v.y), fmaxf(v.z, v.w));
#pragma unroll
    for (int o = 32; o > 0; o >>= 1) m = fmaxf(m, __shfl_down(m, o));
    if (lane == 0) red[wave] = m;
    __syncthreads();
    m = fmaxf(fmaxf(red[0], red[1]), fmaxf(red[2], red[3]));
    __syncthreads();

    const float e0 = __expf(v.x - m), e1 = __expf(v.y - m);
    const float e2 = __expf(v.z - m), e3 = __expf(v.w - m);
    float s = e0 + e1 + e2 + e3;
#pragma unroll
    for (int o = 32; o > 0; o >>= 1) s += __shfl_down(s, o);
    if (lane == 0) red[wave] = s;
    __syncthreads();
    s = red[0] + red[1] + red[2] + red[3];
    const float inv = 1.f / s;

    __bf16* out = Aout + (size_t)row * E_DIM + c;
    out[0] = (__bf16)(e0*inv); out[1] = (__bf16)(e1*inv);
    out[2] = (__bf16)(e2*inv); out[3] = (__bf16)(e3*inv);
}

// LN + residual. X = sum of NPART fp32 partials (stride S*E) + optional
// per-column bias cb. out = LN(X)*g + b + resid.
template <int NPART, bool CB, bool WRITE_BF16>
__global__ __launch_bounds__(256) void ln_residual(
    const float* __restrict__ X, const float* __restrict__ cb,
    const float* __restrict__ resid,
    const float* __restrict__ g, const float* __restrict__ b,
    __bf16* __restrict__ outB, float* __restrict__ outF)
{
    __shared__ float redS[4], redQ[4];
    const int row = blockIdx.x;
    const int tid = threadIdx.x, lane = tid & 63, wave = tid >> 6;
    const size_t SE = (size_t)S_DIM * E_DIM;

    float4 v = ((const float4*)(X + (size_t)row * E_DIM))[tid];
#pragma unroll
    for (int p = 1; p < NPART; ++p) {
        float4 v1 = ((const float4*)(X + (size_t)p * SE + (size_t)row * E_DIM))[tid];
        v.x += v1.x; v.y += v1.y; v.z += v1.z; v.w += v1.w;
    }
    if constexpr (CB) {
        float4 cv = ((const float4*)cb)[tid];
        v.x += cv.x; v.y += cv.y; v.z += cv.z; v.w += cv.w;
    }
    float s = v.x + v.y + v.z + v.w;
    float q = v.x*v.x + v.y*v.y + v.z*v.z + v.w*v.w;
#pragma unroll
    for (int o = 32; o > 0; o >>= 1) { s += __shfl_down(s, o); q += __shfl_down(q, o); }
    if (lane == 0) { redS[wave] = s; redQ[wave] = q; }
    __syncthreads();
    s = redS[0]+redS[1]+redS[2]+redS[3];
    q = redQ[0]+redQ[1]+redQ[2]+redQ[3];

    const float mean = s * (1.f / E_DIM);
    const float var  = q * (1.f / E_DIM) - mean * mean;
    const float rstd = rsqrtf(var + 1e-5f);

    const int c0 = tid * 4;
    float4 rv = ((const float4*)(resid + (size_t)row * E_DIM))[tid];
    const float res[4] = {rv.x, rv.y, rv.z, rv.w};
    const float* vp = &v.x;
#pragma unroll
    for (int i = 0; i < 4; i++) {
        const float o = (vp[i] - mean) * rstd * g[c0+i] + b[c0+i] + res[i];
        outF[(size_t)row * E_DIM + c0 + i] = o;
        if constexpr (WRITE_BF16) outB[(size_t)row * E_DIM + c0 + i] = (__bf16)o;
    }
}

// ---------------------------------------------------------------------------
extern "C" void kernel_launch(void* const* d_in, const int* in_sizes, int n_in,
                              void* d_out, int out_size, void* d_ws, size_t ws_size,
                              hipStream_t stream)
{
    const float* x   = (const float*)d_in[0];
    const float* Wq  = (const float*)d_in[1];
    const float* bq  = (const float*)d_in[2];
    const float* Wk  = (const float*)d_in[3];
    const float* bk  = (const float*)d_in[4];
    const float* Wv  = (const float*)d_in[5];
    const float* bv  = (const float*)d_in[6];
    const float* Wz  = (const float*)d_in[7];
    const float* bz  = (const float*)d_in[8];
    const float* g1  = (const float*)d_in[9];
    const float* b1  = (const float*)d_in[10];
    const float* Wf  = (const float*)d_in[11];
    const float* bfp = (const float*)d_in[12];
    const float* g2  = (const float*)d_in[13];
    const float* b2  = (const float*)d_in[14];

    char* ws = (char*)d_ws;
    const long long EE = (long long)E_DIM * E_DIM;
    const long long SE = (long long)S_DIM * E_DIM;
    const size_t MB = 1024ull * 1024ull;

    // bf16 operand copies / transposes
    __bf16* xb   = (__bf16*)(ws);             //  8 MiB  x [S][E]
    __bf16* Wqb  = (__bf16*)(ws +   8*MB);    // 16 MiB
    __bf16* Wkb  = (__bf16*)(ws +  24*MB);    // 16 MiB
    __bf16* WvT  = (__bf16*)(ws +  40*MB);    // 16 MiB  WvT[h][e][o]
    __bf16* Wzb  = (__bf16*)(ws +  56*MB);    // 16 MiB
    __bf16* Wfb  = (__bf16*)(ws +  72*MB);    //  2 MiB
    __bf16* Gb   = (__bf16*)(ws +  74*MB);    //  2 MiB
    __bf16* PTb  = (__bf16*)(ws +  76*MB);    //  2 MiB
    __bf16* xbT  = (__bf16*)(ws +  78*MB);    //  8 MiB  x^T [E][S]
    float*  u    = (float*) (ws +  86*MB);
    float*  kq   = (float*) (ws +  86*MB +  65536);
    float*  qq   = (float*) (ws +  86*MB + 131072);
    float*  zb   = (float*) (ws +  86*MB + 196608);
    float*  oc   = (float*) (ws +  86*MB + 262144);
    __bf16* LN1b = (__bf16*)(ws +  87*MB);    //  8 MiB
    float*  LN1f = (float*) (ws +  95*MB);    // 16 MiB
    __bf16* Tb   = (__bf16*)(ws + 111*MB);    // 16 MiB  (dead after scores)
    float*  Sc   = (float*) (ws + 127*MB);    // 32 MiB  fp32 (dead after softmax)
    __bf16* Ab   = (__bf16*)(ws + 159*MB);    // 16 MiB  (live: colsum_zb, Y)
    __bf16* Yb   = (__bf16*)(ws + 175*MB);    // 16 MiB  Y[h][g][o] (end 191)
    float*  Gp   = (float*) (ws + 111*MB);    // 32 MiB  8 G partials (before Tb)
    float*  PTp  = (float*) (ws + 111*MB);    // 32 MiB  8 PT partials (Tb/Sc dead)
    float*  Ob   = (float*) (ws + 111*MB);    // 32 MiB  2 partials
    float*  FNb  = (float*) (ws + 111*MB);    // 32 MiB  2 partials

    dim3 blk(256);
    dim3 blk5(512);

    // zero small accumulators (ws is 0xAA-poisoned)
    hipMemsetAsync(u,   0, E_DIM*4, stream);
    hipMemsetAsync(zb,  0, H_DIM*E_DIM*4, stream);

    // operand conversions: x -> xb + xbT (dual), Wv -> WvT (batched), rest cvt
    trans_cvt<true><<<dim3(16, 64, 1), blk, 0, stream>>>(x, xbT, xb, S_DIM, E_DIM);
    cvt_bf16<<<dim3(4096), blk, 0, stream>>>(Wq, Wqb);
    cvt_bf16<<<dim3(4096), blk, 0, stream>>>(Wk, Wkb);
    cvt_bf16<<<dim3(4096), blk, 0, stream>>>(Wz, Wzb);
    cvt_bf16<<<dim3(512),  blk, 0, stream>>>(Wf, Wfb);
    trans_cvt<false><<<dim3(16, 16, 8), blk, 0, stream>>>(Wv, WvT, nullptr, E_DIM, E_DIM);

    // u = colsum(x); kq = Wk u; qq = Wq u  (fp32 exact)
    colsum_u<<<dim3(64), blk, 0, stream>>>(x, u);
    gemv_u<<<dim3(4096), blk, 0, stream>>>(Wk, Wq, u, kq, qq);

    // G = x^T x = xbT(NT) xbT(NT), split-K 8x512 stored partials -> sum -> bf16
    gemmP<1, 0, 0><<<dim3(256), blk5, 0, stream>>>(
        xbT, xbT, (void*)Gp, 512, 512, S_DIM, S_DIM, E_DIM, 0, 0, EE, 4, 0);
    sum8_cvt<<<dim3(512), blk, 0, stream>>>(Gp, Gb);

    // T = Wk_all G  (flat M=8192; G shared, symmetric) -> bf16. 256 blocks.
    gemmP<0, 0, 0><<<dim3(256), blk5, 0, stream>>>(
        Wkb, Gb, (void*)Tb, 1024, 0, E_DIM, E_DIM, E_DIM, 0, 0, 0, 32, 4);
    // scores_raw = T Wq_h^T  (per-head B via m0>>10) -> fp32. 256 blocks.
    gemmP<1, 0, 1><<<dim3(256), blk5, 0, stream>>>(
        Tb, Wqb, (void*)Sc, 1024, 0, E_DIM, E_DIM, E_DIM, 0, EE, 0, 32, 4);
    // A_h = softmax((raw + rank1)/32)
    softmax_fused<<<dim3(H_DIM * E_DIM), blk, 0, stream>>>(Sc, kq, qq, bk, bq, Ab);

    // Y[h][g][o] = sum_f Wz[g][h*E+f] A[h][o][f]  (NT-NT, flat M=8192) -> bf16
    gemmP<0, 1, 1><<<dim3(256), blk5, 0, stream>>>(
        Wzb, Ab, (void*)Yb, 1024, 0, H_DIM * E_DIM, E_DIM, E_DIM, E_DIM, EE, 0, 32, 4);

    // zb = bv^T A ; oc = Wz zb + bz
    colsum_zb<<<dim3(4, 8, 4), blk, 0, stream>>>(Ab, bv, zb);
    gemv_oc<<<dim3(256), blk, 0, stream>>>(Wz, zb, bz, oc);

    // PT[g][e] = sum_{h,o} Y[h][g][o] WvT[h][e][o]  (K-head-batched NT-NT,
    // split-K 8 = one head per z, stored partials) -> sum -> bf16
    gemmP<1, 2, 2><<<dim3(256), blk5, 0, stream>>>(
        Yb, WvT, (void*)PTp, 1024, 1024, E_DIM, E_DIM, E_DIM, EE, EE, EE, 4, 0);
    sum8_cvt<<<dim3(512), blk, 0, stream>>>(PTp, PTb);

    // O partials = x PT^T  (split-K 2x512 -> 2 fp32 partials; bias oc in LN)
    gemmP<1, 0, 0><<<dim3(256), blk5, 0, stream>>>(
        xb, PTb, (void*)Ob, 512, 512, E_DIM, E_DIM, E_DIM, 0, 0, SE, 16, 2);
    // LN1 = LN(O0+O1+oc)*g1+b1 + x
    ln_residual<2, true, true><<<dim3(S_DIM), blk, 0, stream>>>(
        Ob, oc, x, g1, b1, LN1b, LN1f);

    // FN partials = LN1 Wf^T  (split-K 2x512; bias bf in LN)
    gemmP<1, 0, 0><<<dim3(256), blk5, 0, stream>>>(
        LN1b, Wfb, (void*)FNb, 512, 512, E_DIM, E_DIM, E_DIM, 0, 0, SE, 16, 2);
    // out = LN(FN0+FN1+bf)*g2+b2 + LN1
    ln_residual<2, true, false><<<dim3(S_DIM), blk, 0, stream>>>(
        FNb, bfp, LN1f, g2, b2, nullptr, (float*)d_out);
}

// Round 7
// 423.646 us; speedup vs baseline: 1.3446x; 1.0708x over previous
//
#include <hip/hip_runtime.h>

#define S_DIM 4096
#define E_DIM 1024
#define H_DIM 8

typedef __bf16 bf16x8 __attribute__((ext_vector_type(8)));
typedef float  f32x4  __attribute__((ext_vector_type(4)));

// Async global->LDS, 16B per lane. LDS dest is wave-uniform base + lane*16.
__device__ __forceinline__ void async16(const __bf16* gsrc, __bf16* lbase, int lane)
{
#if __has_builtin(__builtin_amdgcn_global_load_lds)
    __builtin_amdgcn_global_load_lds(
        (const __attribute__((address_space(1))) unsigned int*)gsrc,
        (__attribute__((address_space(3))) unsigned int*)lbase, 16, 0, 0);
#else
    ((int4*)lbase)[lane] = *(const int4*)gsrc;
#endif
}

// ---------------------------------------------------------------------------
// 256x128 NT-NT GEMM, subtile-pipelined. 512 thr = 8 waves (4M x 2N), wave
// tile 64x64, BK=64. LDS 96 KiB = 2 rings x 3 subtiles x 16KB
// (alpha = compact low-32 rows of each 64-row wave group, beta = high-32, B).
// v2 (R7): 3 phases per K-tile, 2 barriers per K-tile, stages spread 2+2+2:
//  P0:  vmcnt(2); barrier; read B j0-1 (4 ds) + A-alpha i0-1 (4 ds);
//       stage alpha(kt+1); 8 MFMA acc[0-1][0-1]
//  P1:  read B j2-3 (4 ds); stage B(kt+1); 8 MFMA acc[0-1][2-3]
//  P23: vmcnt(4|0 tail); barrier; read A-beta (4 ds); stage beta(kt+1);
//       16 MFMA acc[2-3][0-3]
// vmcnt proofs (per-wave, 2 loads per stage_sub):
//  P0 needs alpha(kt),B(kt): newer = beta(kt) [prev P23] = 2 -> vmcnt(2).
//  P23 needs beta(kt): newer = alpha',B' [this P0,P1] = 4 -> vmcnt(4);
//  tail iteration stages nothing -> vmcnt(0) once.
// Ring-2 overwrite safety: every stage of kt+1 is issued after a barrier
// (P0-entry / P23-entry) that postdates all waves' completed reads of kt-1
// from the same ring (reads are lgkm-drained before each wave's MFMAs, which
// precede its next barrier arrival). Accumulation order per acc entry is
// unchanged vs v1 -> identical numerics.
// LDS XOR swizzle: slot s of row r holds global 16B-group s ^ (r&7);
// pre-swizzled global source slot, same XOR on read (rule 21).
// Grid 1D: bpz = nMt*8 blocks per K-slice; mtpx>0 -> XCD-colocating decode
// (requires nMt == 8*mtpx). Operand addressing modes:
//  AM/BM = 0: plain      addr = P + row*ld + k
//  AM/BM = 1: M-head     addr = P + (m0>>10)*s + (row&1023 for A)*ld + k
//  AM/BM = 2: K-head     addr = P + (k>>10)*s + row*ld + (k&1023)
// OUT: 0=bf16 store, 1=fp32 store at Cg+zi*sC. No atomics.
// ---------------------------------------------------------------------------
template <int OUT, int AM, int BM>
__global__ __launch_bounds__(512, 1) void gemmP(
    const __bf16* __restrict__ Ag, const __bf16* __restrict__ Bg,
    void* __restrict__ Cg, int Klen, int kPerZ,
    int lda, int ldb, int ldc, long long sA, long long sB, long long sC,
    int nMt, int mtpx)
{
    __shared__ __bf16 sm[2 * 24576];   // ring: alpha[8192] beta[8192] B[8192]

    const int tid  = threadIdx.x;
    const int lane = tid & 63;
    const int wave = tid >> 6;
    const int wm = wave >> 1, wn = wave & 1;   // 4M x 2N
    const int t = lane & 15, q = lane >> 4;

    const int bid = blockIdx.x;
    const int bpz = nMt << 3;
    const int zi  = bid / bpz;
    const int rr  = bid - zi * bpz;
    int mt, nt;
    if (mtpx > 0) {
        const int xcd = rr & 7, s = rr >> 3;
        mt = xcd * mtpx + (s >> 3);
        nt = s & 7;
    } else {
        mt = rr >> 3;
        nt = rr & 7;
    }
    const int m0 = mt * 256;
    const int n0 = nt * 128;
    const int kbeg = zi * kPerZ;
    const int NT = Klen >> 6;                  // K-steps of 64

    // staging: per subtile 128 rows x 64; lane covers row (lane>>3),
    // slot (lane&7), pre-swizzled global slot.
    const int gslot = ((lane & 7) ^ (lane >> 3)) & 7;
    const int lrow  = lane >> 3;

    // which: 0=alpha, 1=beta, 2=B ; 2 async16 per wave each
    auto stage_sub = [&](int kt, int which) {
        __bf16* base = &sm[(kt & 1) * 24576 + which * 8192 + wave * 512];
        const int kk = kbeg + kt * 64;
#pragma unroll
        for (int p = 0; p < 2; p++) {
            const int idx = p * 64 + wave * 8 + lrow;
            const __bf16* g;
            if (which == 2) {
                const int grow = n0 + idx;
                if constexpr (BM == 1)
                    g = Bg + (size_t)(m0 >> 10) * sB + (size_t)grow * ldb + kk + gslot * 8;
                else if constexpr (BM == 2)
                    g = Bg + (size_t)(kk >> 10) * sB + (size_t)grow * ldb + (kk & 1023) + gslot * 8;
                else
                    g = Bg + (size_t)grow * ldb + kk + gslot * 8;
            } else {
                const int grow = m0 + (((idx >> 5) << 6) | (idx & 31)) + (which ? 32 : 0);
                if constexpr (AM == 1)
                    g = Ag + (size_t)(m0 >> 10) * sA + (size_t)(grow & 1023) * lda + kk + gslot * 8;
                else if constexpr (AM == 2)
                    g = Ag + (size_t)(kk >> 10) * sA + (size_t)grow * lda + (kk & 1023) + gslot * 8;
                else
                    g = Ag + (size_t)grow * lda + kk + gslot * 8;
            }
            async16(g, base + p * 4096, lane);
        }
    };

    const int fx = t & 7;                      // read-side XOR (row&7 == t&7)

    f32x4 acc[4][4];
#pragma unroll
    for (int i = 0; i < 4; i++)
#pragma unroll
        for (int j = 0; j < 4; j++) { f32x4 z = {0.f,0.f,0.f,0.f}; acc[i][j] = z; }

    // prologue: stage kt=0 in order alpha, B, beta (beta newest = vmcnt(2) ok)
    stage_sub(0, 0); stage_sub(0, 2); stage_sub(0, 1);

    for (int kt = 0; kt < NT; ++kt) {
        const __bf16* ba = &sm[(kt & 1) * 24576];
        const __bf16* bb = ba + 8192;
        const __bf16* bB = ba + 16384;
        const bool more = (kt + 1 < NT);

        // ---- P0: prove alpha+B; quadrant (i0-1, j0-1) ----
        asm volatile("s_waitcnt vmcnt(2)" ::: "memory");
        __builtin_amdgcn_s_barrier();
        __builtin_amdgcn_sched_barrier(0);

        bf16x8 bfr[4][2], afr[2][2], afr2[2][2];
#pragma unroll
        for (int j = 0; j < 2; j++)
#pragma unroll
            for (int kk = 0; kk < 2; kk++)
                bfr[j][kk] = *(const bf16x8*)&bB[(wn*64 + j*16 + t) * 64 + (((kk<<2)|q) ^ fx) * 8];
#pragma unroll
        for (int i = 0; i < 2; i++)
#pragma unroll
            for (int kk = 0; kk < 2; kk++)
                afr[i][kk] = *(const bf16x8*)&ba[(wm*32 + i*16 + t) * 64 + (((kk<<2)|q) ^ fx) * 8];
        if (more) stage_sub(kt + 1, 0);

        __builtin_amdgcn_s_setprio(1);
#pragma unroll
        for (int i = 0; i < 2; i++)
#pragma unroll
            for (int kk = 0; kk < 2; kk++)
#pragma unroll
                for (int j = 0; j < 2; j++)
                    acc[i][j] = __builtin_amdgcn_mfma_f32_16x16x32_bf16(afr[i][kk], bfr[j][kk], acc[i][j], 0, 0, 0);
        __builtin_amdgcn_s_setprio(0);

        // ---- P1: quadrant (i0-1, j2-3) ----
#pragma unroll
        for (int j = 2; j < 4; j++)
#pragma unroll
            for (int kk = 0; kk < 2; kk++)
                bfr[j][kk] = *(const bf16x8*)&bB[(wn*64 + j*16 + t) * 64 + (((kk<<2)|q) ^ fx) * 8];
        if (more) stage_sub(kt + 1, 2);

        __builtin_amdgcn_s_setprio(1);
#pragma unroll
        for (int i = 0; i < 2; i++)
#pragma unroll
            for (int kk = 0; kk < 2; kk++)
#pragma unroll
                for (int j = 2; j < 4; j++)
                    acc[i][j] = __builtin_amdgcn_mfma_f32_16x16x32_bf16(afr[i][kk], bfr[j][kk], acc[i][j], 0, 0, 0);
        __builtin_amdgcn_s_setprio(0);

        // ---- P23: prove beta; rows i2-3 x all j ----
        if (more) asm volatile("s_waitcnt vmcnt(4)" ::: "memory");
        else      asm volatile("s_waitcnt vmcnt(0)" ::: "memory");
        __builtin_amdgcn_s_barrier();
        __builtin_amdgcn_sched_barrier(0);

#pragma unroll
        for (int i = 0; i < 2; i++)
#pragma unroll
            for (int kk = 0; kk < 2; kk++)
                afr2[i][kk] = *(const bf16x8*)&bb[(wm*32 + i*16 + t) * 64 + (((kk<<2)|q) ^ fx) * 8];
        if (more) stage_sub(kt + 1, 1);

        __builtin_amdgcn_s_setprio(1);
#pragma unroll
        for (int i = 0; i < 2; i++)
#pragma unroll
            for (int kk = 0; kk < 2; kk++)
#pragma unroll
                for (int j = 0; j < 4; j++)
                    acc[i+2][j] = __builtin_amdgcn_mfma_f32_16x16x32_bf16(afr2[i][kk], bfr[j][kk], acc[i+2][j], 0, 0, 0);
        __builtin_amdgcn_s_setprio(0);
    }

#pragma unroll
    for (int i = 0; i < 4; i++) {
        const int rowb = m0 + wm * 64 + i * 16 + q * 4;
#pragma unroll
        for (int j = 0; j < 4; j++) {
            const int col = n0 + wn * 64 + j * 16 + t;
#pragma unroll
            for (int r = 0; r < 4; r++) {
                const float v = acc[i][j][r];
                if constexpr (OUT == 0) {
                    ((__bf16*)Cg)[(size_t)(rowb + r) * ldc + col] = (__bf16)v;
                } else {
                    float* C = (float*)Cg + (size_t)zi * sC;
                    C[(size_t)(rowb + r) * ldc + col] = v;
                }
            }
        }
    }
}

// ---------------------------------------------------------------------------
// Transpose fp32 [R][C] -> bf16 outT [C][R]; optionally also bf16 outN [R][C]
// and (CS) per-column sums atomically added into usum (u = colsum over rows).
// R,C multiples of 64. blockIdx.z batches. LDS 64x65 fp32 tile.
// ---------------------------------------------------------------------------
template <bool WN, bool CS>
__global__ __launch_bounds__(256) void trans_cvt(
    const float* __restrict__ in, __bf16* __restrict__ outT,
    __bf16* __restrict__ outN, float* __restrict__ usum, int R, int C)
{
    __shared__ float t[64][65];
    __shared__ float cs[4][64];
    const size_t base = (size_t)blockIdx.z * R * C;
    const int r0 = blockIdx.y * 64, c0 = blockIdx.x * 64;
    const int tid = threadIdx.x;
    const int r = tid >> 2;
#pragma unroll
    for (int i = 0; i < 4; i++) {
        const int j = (tid & 3) + i * 4;            // float4 chunk 0..15
        float4 v = *(const float4*)(in + base + (size_t)(r0 + r) * C + c0 + j * 4);
        t[r][j*4+0] = v.x; t[r][j*4+1] = v.y; t[r][j*4+2] = v.z; t[r][j*4+3] = v.w;
        if constexpr (WN) {
            union { __bf16 h[4]; unsigned long long q; } u;
            u.h[0]=(__bf16)v.x; u.h[1]=(__bf16)v.y; u.h[2]=(__bf16)v.z; u.h[3]=(__bf16)v.w;
            *(unsigned long long*)(outN + base + (size_t)(r0 + r) * C + c0 + j * 4) = u.q;
        }
    }
    __syncthreads();
#pragma unroll
    for (int i = 0; i < 2; i++) {
        const int idx = tid + 256 * i;              // 0..511
        const int c = idx >> 3, h8 = idx & 7;
        union { __bf16 h[8]; int4 q; } u;
#pragma unroll
        for (int k = 0; k < 8; k++) u.h[k] = (__bf16)t[h8*8+k][c];
        *(int4*)(outT + base + (size_t)(c0 + c) * R + r0 + h8 * 8) = u.q;
    }
    if constexpr (CS) {
        const int c = tid & 63, qg = tid >> 6;
        float s = 0.f;
#pragma unroll
        for (int k = 0; k < 16; k++) s += t[qg*16 + k][c];
        cs[qg][c] = s;
        __syncthreads();
        if (tid < 64)
            atomicAdd(&usum[c0 + tid], cs[0][tid]+cs[1][tid]+cs[2][tid]+cs[3][tid]);
    }
}

// All weight fp32->bf16 conversions in one launch. 12800 blocks:
// [0,4096) Wq, [4096,8192) Wk, [8192,12288) Wz, [12288,12800) Wf.
__global__ __launch_bounds__(256) void cvt_all(
    const float* __restrict__ Wq, const float* __restrict__ Wk,
    const float* __restrict__ Wz, const float* __restrict__ Wf,
    __bf16* __restrict__ Wqb, __bf16* __restrict__ Wkb,
    __bf16* __restrict__ Wzb, __bf16* __restrict__ Wfb)
{
    const int b = blockIdx.x;
    const float* in; __bf16* out; int off;
    if (b < 4096)       { in = Wq; out = Wqb; off = b; }
    else if (b < 8192)  { in = Wk; out = Wkb; off = b - 4096; }
    else if (b < 12288) { in = Wz; out = Wzb; off = b - 8192; }
    else                { in = Wf; out = Wfb; off = b - 12288; }
    const size_t i = ((size_t)off * 256 + threadIdx.x) * 8;
    float4 a = *(const float4*)(in + i);
    float4 c = *(const float4*)(in + i + 4);
    union { __bf16 h[8]; int4 v; } u;
    u.h[0]=(__bf16)a.x; u.h[1]=(__bf16)a.y; u.h[2]=(__bf16)a.z; u.h[3]=(__bf16)a.w;
    u.h[4]=(__bf16)c.x; u.h[5]=(__bf16)c.y; u.h[6]=(__bf16)c.z; u.h[7]=(__bf16)c.w;
    *(int4*)(out + i) = u.v;
}

// sum of 8 fp32 partials (stride EE = 1M elems) -> bf16. grid 512 x 256 thr.
__global__ __launch_bounds__(256) void sum8_cvt(
    const float* __restrict__ P, __bf16* __restrict__ out)
{
    const size_t EE = (size_t)E_DIM * E_DIM;
    const size_t i = ((size_t)blockIdx.x * 256 + threadIdx.x) * 8;
    float4 a = {0.f,0.f,0.f,0.f}, b = {0.f,0.f,0.f,0.f};
#pragma unroll
    for (int p = 0; p < 8; p++) {
        float4 x = *(const float4*)(P + p*EE + i);
        float4 y = *(const float4*)(P + p*EE + i + 4);
        a.x+=x.x; a.y+=x.y; a.z+=x.z; a.w+=x.w;
        b.x+=y.x; b.y+=y.y; b.z+=y.z; b.w+=y.w;
    }
    union { __bf16 h[8]; int4 v; } u;
    u.h[0]=(__bf16)a.x; u.h[1]=(__bf16)a.y; u.h[2]=(__bf16)a.z; u.h[3]=(__bf16)a.w;
    u.h[4]=(__bf16)b.x; u.h[5]=(__bf16)b.y; u.h[6]=(__bf16)b.z; u.h[7]=(__bf16)b.w;
    *(int4*)(out + i) = u.v;
}

// kq[r] = Wk[r,:]·u ; qq[r] = Wq[r,:]·u  (bf16 weights, fp32 u)
__global__ __launch_bounds__(256) void gemv_u(
    const __bf16* __restrict__ Wkb, const __bf16* __restrict__ Wqb,
    const float* __restrict__ u, float* __restrict__ kq, float* __restrict__ qq)
{
    const int gw = blockIdx.x * 4 + (threadIdx.x >> 6);
    const int lane = threadIdx.x & 63;
    const __bf16* W = (gw < 8192) ? Wkb + (size_t)gw * E_DIM
                                  : Wqb + (size_t)(gw - 8192) * E_DIM;
    float s = 0.f;
#pragma unroll
    for (int i = 0; i < 2; i++) {
        bf16x8 w = *(const bf16x8*)(W + lane*16 + i*8);
        float4 z0 = *(const float4*)(u + lane*16 + i*8);
        float4 z1 = *(const float4*)(u + lane*16 + i*8 + 4);
        s += (float)w[0]*z0.x + (float)w[1]*z0.y + (float)w[2]*z0.z + (float)w[3]*z0.w
           + (float)w[4]*z1.x + (float)w[5]*z1.y + (float)w[6]*z1.z + (float)w[7]*z1.w;
    }
#pragma unroll
    for (int o = 32; o > 0; o >>= 1) s += __shfl_down(s, o);
    if (lane == 0) { if (gw < 8192) kq[gw] = s; else qq[gw - 8192] = s; }
}

// zb[h*E+f] = sum_o bv[h][o] * A[h][o][f]; zb pre-zeroed. grid (4,8,4)
__global__ __launch_bounds__(256) void colsum_zb(
    const __bf16* __restrict__ Ab, const float* __restrict__ bv, float* __restrict__ zb)
{
    const int h = blockIdx.y;
    const int f = blockIdx.x * 256 + threadIdx.x;
    const int o0 = blockIdx.z * 256;
    const __bf16* A = Ab + (size_t)h * E_DIM * E_DIM + (size_t)o0 * E_DIM + f;
    const float* bvh = bv + h * E_DIM + o0;
    float s = 0.f;
    for (int o = 0; o < 256; o++) s += bvh[o] * (float)A[(size_t)o * E_DIM];
    atomicAdd(&zb[h * E_DIM + f], s);
}

// oc[g] = zb·Wz[g,:] + bz[g]   (K=8192, one wave per row)
__global__ __launch_bounds__(256) void gemv_oc(
    const float* __restrict__ Wz, const float* __restrict__ zb,
    const float* __restrict__ bz, float* __restrict__ oc)
{
    const int gw = blockIdx.x * 4 + (threadIdx.x >> 6);
    const int lane = threadIdx.x & 63;
    const float* W = Wz + (size_t)gw * (H_DIM * E_DIM);
    float s = 0.f;
#pragma unroll
    for (int i = 0; i < 32; i++) {
        float4 w = *(const float4*)(W + i*256 + lane*4);
        float4 z = *(const float4*)(zb + i*256 + lane*4);
        s += w.x*z.x + w.y*z.y + w.z*z.z + w.w*z.w;
    }
#pragma unroll
    for (int o = 32; o > 0; o >>= 1) s += __shfl_down(s, o);
    if (lane == 0) oc[gw] = s + bz[gw];
}

// softmax over f with fused rank-1 bias terms and 1/sqrt(E) scale.
__global__ __launch_bounds__(256) void softmax_fused(
    const float* __restrict__ Sc, const float* __restrict__ kq,
    const float* __restrict__ qq, const float* __restrict__ bk,
    const float* __restrict__ bq, __bf16* __restrict__ Aout)
{
    __shared__ float red[4];
    const int row = blockIdx.x;
    const int h = row >> 10;
    const int tid = threadIdx.x, lane = tid & 63, wave = tid >> 6;
    const float kqj = kq[row], bkj = bk[row];
    const float cst = (float)S_DIM * bkj;

    float4 v = ((const float4*)(Sc + (size_t)row * E_DIM))[tid];
    const int c = tid * 4;
    float4 qv = *(const float4*)(qq + (h << 10) + c);
    float4 bv = *(const float4*)(bq + (h << 10) + c);
    v.x = (v.x + kqj*bv.x + bkj*qv.x + cst*bv.x) * 0.03125f;
    v.y = (v.y + kqj*bv.y + bkj*qv.y + cst*bv.y) * 0.03125f;
    v.z = (v.z + kqj*bv.z + bkj*qv.z + cst*bv.z) * 0.03125f;
    v.w = (v.w + kqj*bv.w + bkj*qv.w + cst*bv.w) * 0.03125f;

    float m = fmaxf(fmaxf(v.x, v.y), fmaxf(v.z, v.w));
#pragma unroll
    for (int o = 32; o > 0; o >>= 1) m = fmaxf(m, __shfl_down(m, o));
    if (lane == 0) red[wave] = m;
    __syncthreads();
    m = fmaxf(fmaxf(red[0], red[1]), fmaxf(red[2], red[3]));
    __syncthreads();

    const float e0 = __expf(v.x - m), e1 = __expf(v.y - m);
    const float e2 = __expf(v.z - m), e3 = __expf(v.w - m);
    float s = e0 + e1 + e2 + e3;
#pragma unroll
    for (int o = 32; o > 0; o >>= 1) s += __shfl_down(s, o);
    if (lane == 0) red[wave] = s;
    __syncthreads();
    s = red[0] + red[1] + red[2] + red[3];
    const float inv = 1.f / s;

    __bf16* out = Aout + (size_t)row * E_DIM + c;
    out[0] = (__bf16)(e0*inv); out[1] = (__bf16)(e1*inv);
    out[2] = (__bf16)(e2*inv); out[3] = (__bf16)(e3*inv);
}

// LN + residual. X = sum of NPART fp32 partials (stride S*E) + optional
// per-column bias cb. out = LN(X)*g + b + resid.
template <int NPART, bool CB, bool WRITE_BF16>
__global__ __launch_bounds__(256) void ln_residual(
    const float* __restrict__ X, const float* __restrict__ cb,
    const float* __restrict__ resid,
    const float* __restrict__ g, const float* __restrict__ b,
    __bf16* __restrict__ outB, float* __restrict__ outF)
{
    __shared__ float redS[4], redQ[4];
    const int row = blockIdx.x;
    const int tid = threadIdx.x, lane = tid & 63, wave = tid >> 6;
    const size_t SE = (size_t)S_DIM * E_DIM;

    float4 v = ((const float4*)(X + (size_t)row * E_DIM))[tid];
#pragma unroll
    for (int p = 1; p < NPART; ++p) {
        float4 v1 = ((const float4*)(X + (size_t)p * SE + (size_t)row * E_DIM))[tid];
        v.x += v1.x; v.y += v1.y; v.z += v1.z; v.w += v1.w;
    }
    if constexpr (CB) {
        float4 cv = ((const float4*)cb)[tid];
        v.x += cv.x; v.y += cv.y; v.z += cv.z; v.w += cv.w;
    }
    float s = v.x + v.y + v.z + v.w;
    float q = v.x*v.x + v.y*v.y + v.z*v.z + v.w*v.w;
#pragma unroll
    for (int o = 32; o > 0; o >>= 1) { s += __shfl_down(s, o); q += __shfl_down(q, o); }
    if (lane == 0) { redS[wave] = s; redQ[wave] = q; }
    __syncthreads();
    s = redS[0]+redS[1]+redS[2]+redS[3];
    q = redQ[0]+redQ[1]+redQ[2]+redQ[3];

    const float mean = s * (1.f / E_DIM);
    const float var  = q * (1.f / E_DIM) - mean * mean;
    const float rstd = rsqrtf(var + 1e-5f);

    const int c0 = tid * 4;
    float4 rv = ((const float4*)(resid + (size_t)row * E_DIM))[tid];
    const float res[4] = {rv.x, rv.y, rv.z, rv.w};
    const float* vp = &v.x;
#pragma unroll
    for (int i = 0; i < 4; i++) {
        const float o = (vp[i] - mean) * rstd * g[c0+i] + b[c0+i] + res[i];
        outF[(size_t)row * E_DIM + c0 + i] = o;
        if constexpr (WRITE_BF16) outB[(size_t)row * E_DIM + c0 + i] = (__bf16)o;
    }
}

// ---------------------------------------------------------------------------
extern "C" void kernel_launch(void* const* d_in, const int* in_sizes, int n_in,
                              void* d_out, int out_size, void* d_ws, size_t ws_size,
                              hipStream_t stream)
{
    const float* x   = (const float*)d_in[0];
    const float* Wq  = (const float*)d_in[1];
    const float* bq  = (const float*)d_in[2];
    const float* Wk  = (const float*)d_in[3];
    const float* bk  = (const float*)d_in[4];
    const float* Wv  = (const float*)d_in[5];
    const float* bv  = (const float*)d_in[6];
    const float* Wz  = (const float*)d_in[7];
    const float* bz  = (const float*)d_in[8];
    const float* g1  = (const float*)d_in[9];
    const float* b1  = (const float*)d_in[10];
    const float* Wf  = (const float*)d_in[11];
    const float* bfp = (const float*)d_in[12];
    const float* g2  = (const float*)d_in[13];
    const float* b2  = (const float*)d_in[14];

    char* ws = (char*)d_ws;
    const long long EE = (long long)E_DIM * E_DIM;
    const long long SE = (long long)S_DIM * E_DIM;
    const size_t MB = 1024ull * 1024ull;

    // bf16 operand copies / transposes
    __bf16* xb   = (__bf16*)(ws);             //  8 MiB  x [S][E]
    __bf16* Wqb  = (__bf16*)(ws +   8*MB);    // 16 MiB
    __bf16* Wkb  = (__bf16*)(ws +  24*MB);    // 16 MiB
    __bf16* WvT  = (__bf16*)(ws +  40*MB);    // 16 MiB  WvT[h][e][o]
    __bf16* Wzb  = (__bf16*)(ws +  56*MB);    // 16 MiB
    __bf16* Wfb  = (__bf16*)(ws +  72*MB);    //  2 MiB
    __bf16* Gb   = (__bf16*)(ws +  74*MB);    //  2 MiB
    __bf16* PTb  = (__bf16*)(ws +  76*MB);    //  2 MiB
    __bf16* xbT  = (__bf16*)(ws +  78*MB);    //  8 MiB  x^T [E][S]
    float*  u    = (float*) (ws +  86*MB);
    float*  kq   = (float*) (ws +  86*MB +  65536);
    float*  qq   = (float*) (ws +  86*MB + 131072);
    float*  zb   = (float*) (ws +  86*MB + 196608);
    float*  oc   = (float*) (ws +  86*MB + 262144);
    __bf16* LN1b = (__bf16*)(ws +  87*MB);    //  8 MiB
    float*  LN1f = (float*) (ws +  95*MB);    // 16 MiB
    __bf16* Tb   = (__bf16*)(ws + 111*MB);    // 16 MiB  (dead after scores)
    float*  Sc   = (float*) (ws + 127*MB);    // 32 MiB  fp32 (dead after softmax)
    __bf16* Ab   = (__bf16*)(ws + 159*MB);    // 16 MiB  (live: colsum_zb, Y)
    __bf16* Yb   = (__bf16*)(ws + 175*MB);    // 16 MiB  Y[h][g][o] (end 191)
    float*  Gp   = (float*) (ws + 111*MB);    // 32 MiB  8 G partials (before Tb)
    float*  PTp  = (float*) (ws + 111*MB);    // 32 MiB  8 PT partials (Tb/Sc dead)
    float*  Ob   = (float*) (ws + 111*MB);    // 32 MiB  2 partials
    float*  FNb  = (float*) (ws + 111*MB);    // 32 MiB  2 partials

    dim3 blk(256);
    dim3 blk5(512);

    // zero small accumulators (ws is 0xAA-poisoned)
    hipMemsetAsync(u,   0, E_DIM*4, stream);
    hipMemsetAsync(zb,  0, H_DIM*E_DIM*4, stream);

    // conversions: x -> xb + xbT + u (fused colsum), weights in one launch,
    // Wv -> WvT (batched transpose)
    trans_cvt<true, true><<<dim3(16, 64, 1), blk, 0, stream>>>(
        x, xbT, xb, u, S_DIM, E_DIM);
    cvt_all<<<dim3(12800), blk, 0, stream>>>(Wq, Wk, Wz, Wf, Wqb, Wkb, Wzb, Wfb);
    trans_cvt<false, false><<<dim3(16, 16, 8), blk, 0, stream>>>(
        Wv, WvT, nullptr, nullptr, E_DIM, E_DIM);

    // kq = Wk u; qq = Wq u  (bf16 weights)
    gemv_u<<<dim3(4096), blk, 0, stream>>>(Wkb, Wqb, u, kq, qq);

    // G = x^T x = xbT(NT) xbT(NT), split-K 8x512 stored partials -> sum -> bf16
    gemmP<1, 0, 0><<<dim3(256), blk5, 0, stream>>>(
        xbT, xbT, (void*)Gp, 512, 512, S_DIM, S_DIM, E_DIM, 0, 0, EE, 4, 0);
    sum8_cvt<<<dim3(512), blk, 0, stream>>>(Gp, Gb);

    // T = Wk_all G  (flat M=8192; G shared, symmetric) -> bf16. 256 blocks.
    gemmP<0, 0, 0><<<dim3(256), blk5, 0, stream>>>(
        Wkb, Gb, (void*)Tb, 1024, 0, E_DIM, E_DIM, E_DIM, 0, 0, 0, 32, 4);
    // scores_raw = T Wq_h^T  (per-head B via m0>>10) -> fp32. 256 blocks.
    gemmP<1, 0, 1><<<dim3(256), blk5, 0, stream>>>(
        Tb, Wqb, (void*)Sc, 1024, 0, E_DIM, E_DIM, E_DIM, 0, EE, 0, 32, 4);
    // A_h = softmax((raw + rank1)/32)
    softmax_fused<<<dim3(H_DIM * E_DIM), blk, 0, stream>>>(Sc, kq, qq, bk, bq, Ab);

    // Y[h][g][o] = sum_f Wz[g][h*E+f] A[h][o][f]  (NT-NT, flat M=8192) -> bf16
    gemmP<0, 1, 1><<<dim3(256), blk5, 0, stream>>>(
        Wzb, Ab, (void*)Yb, 1024, 0, H_DIM * E_DIM, E_DIM, E_DIM, E_DIM, EE, 0, 32, 4);

    // zb = bv^T A ; oc = Wz zb + bz
    colsum_zb<<<dim3(4, 8, 4), blk, 0, stream>>>(Ab, bv, zb);
    gemv_oc<<<dim3(256), blk, 0, stream>>>(Wz, zb, bz, oc);

    // PT[g][e] = sum_{h,o} Y[h][g][o] WvT[h][e][o]  (K-head-batched NT-NT,
    // split-K 8 = one head per z, stored partials) -> sum -> bf16
    gemmP<1, 2, 2><<<dim3(256), blk5, 0, stream>>>(
        Yb, WvT, (void*)PTp, 1024, 1024, E_DIM, E_DIM, E_DIM, EE, EE, EE, 4, 0);
    sum8_cvt<<<dim3(512), blk, 0, stream>>>(PTp, PTb);

    // O partials = x PT^T  (split-K 2x512 -> 2 fp32 partials; bias oc in LN)
    gemmP<1, 0, 0><<<dim3(256), blk5, 0, stream>>>(
        xb, PTb, (void*)Ob, 512, 512, E_DIM, E_DIM, E_DIM, 0, 0, SE, 16, 2);
    // LN1 = LN(O0+O1+oc)*g1+b1 + x
    ln_residual<2, true, true><<<dim3(S_DIM), blk, 0, stream>>>(
        Ob, oc, x, g1, b1, LN1b, LN1f);

    // FN partials = LN1 Wf^T  (split-K 2x512; bias bf in LN)
    gemmP<1, 0, 0><<<dim3(256), blk5, 0, stream>>>(
        LN1b, Wfb, (void*)FNb, 512, 512, E_DIM, E_DIM, E_DIM, 0, 0, SE, 16, 2);
    // out = LN(FN0+FN1+bf)*g2+b2 + LN1
    ln_residual<2, true, false><<<dim3(S_DIM), blk, 0, stream>>>(
        FNb, bfp, LN1f, g2, b2, nullptr, (float*)d_out);
}